// Round 12
// baseline (316.722 us; speedup 1.0000x reference)
//
#include <hip/hip_runtime.h>
#include <hip/hip_bf16.h>

#define D_MODEL 1024
#define N_HEADS 16
#define DEPTH   64
#define D_FF    4096
#define BATCH   2
#define SEQ     2048
#define NTOK    (BATCH * SEQ)   // 4096
#define EPS     1e-5f

typedef __attribute__((ext_vector_type(8))) short short8;
typedef __attribute__((ext_vector_type(4))) float f32x4;
typedef __attribute__((ext_vector_type(4))) unsigned short ushort4v;
typedef __attribute__((ext_vector_type(8))) unsigned short ushort8v;

__device__ __forceinline__ unsigned short f2bf(float f) {
    union { __hip_bfloat16 h; unsigned short u; } cv;
    cv.h = __float2bfloat16(f);   // RNE
    return cv.u;
}

__device__ __forceinline__ float bf2f(unsigned short u) {
    union { float f; unsigned int i; } c;
    c.i = (unsigned int)u << 16;
    return c.f;
}

__device__ __forceinline__ float exp2_fast(float x) {
    float r;
    asm("v_exp_f32 %0, %1" : "=v"(r) : "v"(x));
    return r;
}

__device__ __forceinline__ void gload16(const unsigned short* g, unsigned short* lds) {
    __builtin_amdgcn_global_load_lds(
        (const __attribute__((address_space(1))) void*)g,
        (__attribute__((address_space(3))) void*)lds, 16, 0, 0);
}

// ---------------------------------------------------------------------------
// fused prep: all weight transposes (f32->bf16), bias concat, x cast.
// ---------------------------------------------------------------------------
__device__ __forceinline__ void tc_tile(
    const float* __restrict__ W, unsigned short* __restrict__ WT,
    int K, int N, int bn64, int bk64, int tid, float (*t)[65])
{
    const int bk = bk64 * 64, bn = bn64 * 64;
    const int c4 = tid & 15, r0 = tid >> 4;
#pragma unroll
    for (int i = 0; i < 4; ++i) {
        int k = r0 + i * 16;
        f32x4 v = *(const f32x4*)&W[(size_t)(bk + k) * N + bn + c4 * 4];
#pragma unroll
        for (int jj = 0; jj < 4; ++jj) t[k][c4 * 4 + jj] = v[jj];
    }
    __syncthreads();
#pragma unroll
    for (int i = 0; i < 4; ++i) {
        int n = r0 + i * 16;
        ushort4v o;
#pragma unroll
        for (int jj = 0; jj < 4; ++jj) o[jj] = f2bf(t[c4 * 4 + jj][n]);
        *(ushort4v*)&WT[(size_t)(bn + n) * K + bk + c4 * 4] = o;
    }
}

__global__ __launch_bounds__(256) void prep_kernel(
    const float* __restrict__ wq_w, const float* __restrict__ wk_w,
    const float* __restrict__ wv_w, const float* __restrict__ wo_w,
    const float* __restrict__ ffn_w1, const float* __restrict__ ffn_w2,
    const float* __restrict__ wq_b, const float* __restrict__ wk_b,
    const float* __restrict__ wv_b, const float* __restrict__ x,
    unsigned short* __restrict__ wqkvT, unsigned short* __restrict__ woT,
    unsigned short* __restrict__ w1T, unsigned short* __restrict__ w2T,
    float* __restrict__ biasqkv, unsigned short* __restrict__ actb)
{
    __shared__ float t[64][65];
    const int idx = blockIdx.x, tid = threadIdx.x;

    if (idx < 1024) {
        const int wsel = idx >> 8, rel = idx & 255;
        const float* W = (wsel == 0) ? wq_w : (wsel == 1) ? wk_w : (wsel == 2) ? wv_w : wo_w;
        unsigned short* WT = (wsel == 3) ? woT : (wqkvT + (size_t)wsel * 1024 * 1024);
        tc_tile(W, WT, 1024, 1024, rel & 15, rel >> 4, tid, t);
    } else if (idx < 2048) {
        const int rel = idx - 1024;
        tc_tile(ffn_w1, w1T, 1024, 4096, rel & 63, rel >> 6, tid, t);
    } else if (idx < 3072) {
        const int rel = idx - 2048;
        tc_tile(ffn_w2, w2T, 4096, 1024, rel & 15, rel >> 4, tid, t);
    } else if (idx < 3084) {
        const int i = (idx - 3072) * 256 + tid;
        if (i < 1024) biasqkv[i] = wq_b[i];
        else if (i < 2048) biasqkv[i] = wk_b[i - 1024];
        else if (i < 3072) biasqkv[i] = wv_b[i - 2048];
    } else {
        const int i = ((idx - 3084) * 256 + tid) * 8;
        f32x4 a = *(const f32x4*)&x[i];
        f32x4 b = *(const f32x4*)&x[i + 4];
        ushort8v o;
        o[0] = f2bf(a[0]); o[1] = f2bf(a[1]); o[2] = f2bf(a[2]); o[3] = f2bf(a[3]);
        o[4] = f2bf(b[0]); o[5] = f2bf(b[1]); o[6] = f2bf(b[2]); o[7] = f2bf(b[3]);
        *(ushort8v*)&actb[i] = o;
    }
}

// ---------------------------------------------------------------------------
// V^T extraction: QKV bf16 [tok][3072] (V at col 2048+) -> Vt[bh][64][2048]
// ---------------------------------------------------------------------------
__global__ __launch_bounds__(256) void vtrans_kernel(
    const unsigned short* __restrict__ QKV, unsigned short* __restrict__ Vt)
{
    __shared__ unsigned short T[64][72];
    const int st = blockIdx.x * 64;
    const int h = blockIdx.y, b = blockIdx.z;
    const int tid = threadIdx.x;
    const size_t tok0 = (size_t)b * SEQ;
    const int LD = 3 * D_MODEL;
    const int r = tid >> 3, c8 = (tid & 7) * 8;
#pragma unroll
    for (int p = 0; p < 2; ++p) {
        int row = p * 32 + r;
        *(ushort8v*)&T[row][c8] =
            *(const ushort8v*)&QKV[(tok0 + st + row) * LD + 2048 + h * 64 + c8];
    }
    __syncthreads();
    const int bh = b * N_HEADS + h;
#pragma unroll
    for (int p = 0; p < 2; ++p) {
        int d = p * 32 + r;
        ushort8v o;
#pragma unroll
        for (int e = 0; e < 8; ++e) o[e] = T[c8 + e][d];
        *(ushort8v*)&Vt[((size_t)bh * 64 + d) * SEQ + st + c8] = o;
    }
}

// ---------------------------------------------------------------------------
// 256x256 pipelined bf16 MFMA GEMM with optional split-K.
// ---------------------------------------------------------------------------
__global__ __launch_bounds__(512, 2) void gemm256_kernel(
    const unsigned short* __restrict__ A, const unsigned short* __restrict__ BT,
    const float* __restrict__ bias, float* __restrict__ C,
    unsigned short* __restrict__ Cb,
    int M, int N, int lda, int kLen, int ksplit, int relu, int out_bf)
{
    __shared__ unsigned short As[2][256 * 64];
    __shared__ unsigned short Bs[2][256 * 64];
    const int tid = threadIdx.x;
    const int lane = tid & 63, w = tid >> 6;
    const int wr = w >> 2, wc = w & 3;
    const int lr = lane & 15, g = lane >> 4;

    // XCD-aware block swizzle (bijective when nwg % 8 == 0)
    const int nwg = gridDim.x;
    int wg = blockIdx.x;
    if ((nwg & 7) == 0) wg = (wg & 7) * (nwg >> 3) + (wg >> 3);
    if (ksplit > 1) {
        const int ntile = nwg / ksplit;
        const int split = wg / ntile;
        wg = wg % ntile;
        A  += (size_t)split * kLen;
        BT += (size_t)split * kLen;
        C  += (size_t)split * M * N;
        Cb += (size_t)split * M * N;
    }
    const int gx = N >> 8;
    const int bm = (wg / gx) * 256, bn = (wg % gx) * 256;

    const int srow = (w << 3) + (lane >> 3);
    const int scol = ((lane & 7) ^ (lane >> 3)) << 3;
    const int ldst = (w << 9);

#define STG(P, Xs, bufi, hf, rb, k0)                                            \
    {                                                                            \
        gload16(P + (size_t)((rb) + (hf) * 128 + srow) * lda + (k0) + scol,      \
                &Xs[bufi][(hf) * 8192 + ldst]);                                  \
        gload16(P + (size_t)((rb) + (hf) * 128 + 64 + srow) * lda + (k0) + scol, \
                &Xs[bufi][(hf) * 8192 + 4096 + ldst]);                           \
    }

    const int NS = kLen >> 6;
    f32x4 acc[8][4] = {};

    STG(A,  As, 0, 0, bm, 0); STG(A,  As, 0, 1, bm, 0);
    STG(BT, Bs, 0, 0, bn, 0); STG(BT, Bs, 0, 1, bn, 0);
    if (NS > 1) { STG(BT, Bs, 1, 0, bn, 64); STG(BT, Bs, 1, 1, bn, 64); }
    asm volatile("s_waitcnt vmcnt(4)" ::: "memory");
    __builtin_amdgcn_s_barrier();
    asm volatile("" ::: "memory");

    int buf = 0;
    short8 af[4][2], b0[2][2], b1[2][2];
    for (int s = 0; s < NS; ++s) {
        const int kn1 = (s + 1) << 6, kn2 = (s + 2) << 6;

        // ---- phase 1
#pragma unroll
        for (int i = 0; i < 4; ++i)
#pragma unroll
            for (int kk = 0; kk < 2; ++kk)
                af[i][kk] = *(const short8*)&As[buf][(wr * 128 + i * 16 + lr) * 64
                                                    + (((kk * 4 + g) ^ (lr & 7)) << 3)];
#pragma unroll
        for (int j = 0; j < 2; ++j)
#pragma unroll
            for (int kk = 0; kk < 2; ++kk)
                b0[j][kk] = *(const short8*)&Bs[buf][(wc * 64 + j * 16 + lr) * 64
                                                    + (((kk * 4 + g) ^ (lr & 7)) << 3)];
        if (s + 1 < NS) STG(A, As, buf ^ 1, 0, bm, kn1);
        asm volatile("" ::: "memory");
        __builtin_amdgcn_s_barrier();
        asm volatile("" ::: "memory");
        __builtin_amdgcn_s_setprio(1);
#pragma unroll
        for (int i = 0; i < 4; ++i)
#pragma unroll
            for (int j = 0; j < 2; ++j) {
                acc[i][j] = __builtin_amdgcn_mfma_f32_16x16x32_bf16(af[i][0], b0[j][0], acc[i][j], 0, 0, 0);
                acc[i][j] = __builtin_amdgcn_mfma_f32_16x16x32_bf16(af[i][1], b0[j][1], acc[i][j], 0, 0, 0);
            }
        __builtin_amdgcn_s_setprio(0);
        asm volatile("" ::: "memory");
        __builtin_amdgcn_s_barrier();
        asm volatile("" ::: "memory");

        // ---- phase 2
#pragma unroll
        for (int j = 0; j < 2; ++j)
#pragma unroll
            for (int kk = 0; kk < 2; ++kk)
                b1[j][kk] = *(const short8*)&Bs[buf][(wc * 64 + (j + 2) * 16 + lr) * 64
                                                    + (((kk * 4 + g) ^ (lr & 7)) << 3)];
        if (s + 1 < NS) STG(A, As, buf ^ 1, 1, bm, kn1);
        asm volatile("" ::: "memory");
        __builtin_amdgcn_s_barrier();
        asm volatile("" ::: "memory");
        __builtin_amdgcn_s_setprio(1);
#pragma unroll
        for (int i = 0; i < 4; ++i)
#pragma unroll
            for (int j = 0; j < 2; ++j) {
                acc[i][j + 2] = __builtin_amdgcn_mfma_f32_16x16x32_bf16(af[i][0], b1[j][0], acc[i][j + 2], 0, 0, 0);
                acc[i][j + 2] = __builtin_amdgcn_mfma_f32_16x16x32_bf16(af[i][1], b1[j][1], acc[i][j + 2], 0, 0, 0);
            }
        __builtin_amdgcn_s_setprio(0);
        asm volatile("" ::: "memory");
        __builtin_amdgcn_s_barrier();
        asm volatile("" ::: "memory");

        // ---- phase 3
#pragma unroll
        for (int i = 0; i < 4; ++i)
#pragma unroll
            for (int kk = 0; kk < 2; ++kk)
                af[i][kk] = *(const short8*)&As[buf][(wr * 128 + 64 + i * 16 + lr) * 64
                                                    + (((kk * 4 + g) ^ (lr & 7)) << 3)];
        if (s + 2 < NS) STG(BT, Bs, buf, 0, bn, kn2);
        asm volatile("" ::: "memory");
        __builtin_amdgcn_s_barrier();
        asm volatile("" ::: "memory");
        __builtin_amdgcn_s_setprio(1);
#pragma unroll
        for (int i = 0; i < 4; ++i)
#pragma unroll
            for (int j = 0; j < 2; ++j) {
                acc[i + 4][j] = __builtin_amdgcn_mfma_f32_16x16x32_bf16(af[i][0], b0[j][0], acc[i + 4][j], 0, 0, 0);
                acc[i + 4][j] = __builtin_amdgcn_mfma_f32_16x16x32_bf16(af[i][1], b0[j][1], acc[i + 4][j], 0, 0, 0);
            }
        __builtin_amdgcn_s_setprio(0);
        asm volatile("" ::: "memory");
        __builtin_amdgcn_s_barrier();
        asm volatile("" ::: "memory");

        // ---- phase 4
        if (s + 2 < NS) STG(BT, Bs, buf, 1, bn, kn2);
        asm volatile("" ::: "memory");
        __builtin_amdgcn_s_barrier();
        asm volatile("" ::: "memory");
        __builtin_amdgcn_s_setprio(1);
#pragma unroll
        for (int i = 0; i < 4; ++i)
#pragma unroll
            for (int j = 0; j < 2; ++j) {
                acc[i + 4][j + 2] = __builtin_amdgcn_mfma_f32_16x16x32_bf16(af[i][0], b1[j][0], acc[i + 4][j + 2], 0, 0, 0);
                acc[i + 4][j + 2] = __builtin_amdgcn_mfma_f32_16x16x32_bf16(af[i][1], b1[j][1], acc[i + 4][j + 2], 0, 0, 0);
            }
        __builtin_amdgcn_s_setprio(0);
        asm volatile("s_waitcnt vmcnt(4)" ::: "memory");
        __builtin_amdgcn_s_barrier();
        asm volatile("" ::: "memory");

        buf ^= 1;
    }
#undef STG

#pragma unroll
    for (int i = 0; i < 8; ++i)
#pragma unroll
        for (int j = 0; j < 4; ++j) {
            const int col = bn + wc * 64 + j * 16 + lr;
            const float bv = bias ? bias[col] : 0.f;
#pragma unroll
            for (int r = 0; r < 4; ++r) {
                const int row = bm + wr * 128 + i * 16 + g * 4 + r;
                float v = acc[i][j][r] + bv;
                if (relu) v = fmaxf(v, 0.f);
                if (out_bf) Cb[(size_t)row * N + col] = f2bf(v);
                else        C [(size_t)row * N + col] = v;
            }
        }
}

// ---------------------------------------------------------------------------
// bf16 MFMA GEMM (m97 structure), 128x128 tile, optional split-K via blockIdx.z
// ---------------------------------------------------------------------------
__global__ __launch_bounds__(256) void gemm_bt_kernel(
    const unsigned short* __restrict__ A, const unsigned short* __restrict__ BT,
    const float* __restrict__ bias, float* __restrict__ C,
    unsigned short* __restrict__ Cb,
    int M, int N, int lda, int kLen, int relu, int out_bf)
{
    __shared__ unsigned short As[128 * 64];
    __shared__ unsigned short Bs[128 * 64];
    const int tid = threadIdx.x;
    const int lane = tid & 63, wv = tid >> 6;
    const int wr = wv >> 1, wc = wv & 1;
    const int bm = blockIdx.y * 128, bn = blockIdx.x * 128;
    const int kbase = blockIdx.z * kLen;
    const int lr = lane & 15, lk = (lane >> 4) << 3;

    C  += (size_t)blockIdx.z * M * N;
    Cb += (size_t)blockIdx.z * M * N;

    f32x4 acc[4][4] = {};

    for (int kt = 0; kt < kLen; kt += 64) {
#pragma unroll
        for (int c = 0; c < 4; ++c) {
            int e = c * 2048 + tid * 8;
            int row = e >> 6, k = e & 63;
            gload16(A  + (size_t)(bm + row) * lda + kbase + kt + k, As + c * 2048 + wv * 512);
            gload16(BT + (size_t)(bn + row) * lda + kbase + kt + k, Bs + c * 2048 + wv * 512);
        }
        __syncthreads();
#pragma unroll
        for (int kk = 0; kk < 2; ++kk) {
            short8 af[4], bfr[4];
#pragma unroll
            for (int i = 0; i < 4; ++i) {
                af[i]  = *(const short8*)&As[(wr * 64 + i * 16 + lr) * 64 + kk * 32 + lk];
                bfr[i] = *(const short8*)&Bs[(wc * 64 + i * 16 + lr) * 64 + kk * 32 + lk];
            }
#pragma unroll
            for (int i = 0; i < 4; ++i)
#pragma unroll
                for (int j = 0; j < 4; ++j)
                    acc[i][j] = __builtin_amdgcn_mfma_f32_16x16x32_bf16(
                        af[i], bfr[j], acc[i][j], 0, 0, 0);
        }
        __syncthreads();
    }

    const int r0 = bm + wr * 64, c0 = bn + wc * 64;
    const int rq = (lane >> 4) * 4;
#pragma unroll
    for (int i = 0; i < 4; ++i)
#pragma unroll
        for (int j = 0; j < 4; ++j) {
            int col = c0 + j * 16 + lr;
            float bv = bias ? bias[col] : 0.f;
#pragma unroll
            for (int r = 0; r < 4; ++r) {
                int row = r0 + i * 16 + rq + r;
                float v = acc[i][j][r] + bv;
                if (relu) v = fmaxf(v, 0.f);
                if (out_bf) Cb[(size_t)row * N + col] = f2bf(v);
                else        C [(size_t)row * N + col] = v;
            }
        }
}

// ---------------------------------------------------------------------------
// MFMA flash attention, split-S=2. 4 waves x 32 q (block = 128 q), KVBLK=64.
// Reg-staged K/V (T14): plain global loads into registers issued at tile top,
// ds_write (swizzled) after the read-release barrier -> HBM latency hides
// under compute; single-buffered K/V LDS (32.3KB -> 4 blocks/CU).
// Deferred-max online softmax (stale m_, init 20); rescale (rare) after PV.
// Row-sum l via ones-matrix MFMA. Outputs unnormalized O (bf16) + m + l.
// ---------------------------------------------------------------------------
__global__ __launch_bounds__(256, 4) void attn_mfma_kernel(
    const unsigned short* __restrict__ QKV,
    const unsigned short* __restrict__ Vt,
    const int* __restrict__ mask,
    unsigned short* __restrict__ Op, float* __restrict__ mA, float* __restrict__ lA)
{
    const int tid = threadIdx.x;
    const int lane = tid & 63, w = tid >> 6;
    const int lr = lane & 15, g = lane >> 4;   // g in 0..3
    const int qt = blockIdx.x * 128;
    const int h = blockIdx.y;
    const int b = blockIdx.z >> 1, sp = blockIdx.z & 1;
    const int bh = b * N_HEADS + h;
    const size_t tok0 = (size_t)b * SEQ;
    const int kvb0 = sp * (SEQ / 2);
    const int LD = 3 * D_MODEL;
    const float C1 = 0.18033688f;   // 0.125 * log2(e)

    __shared__ unsigned short Ks[64 * 64];      // [kv][d], 16B-slot swizzled
    __shared__ unsigned short Vs[64 * 64];      // [d][kv], 16B-slot swizzled
    __shared__ unsigned short Ps[4][32 * 64];   // per-wave P [q][kv], swizzled
    __shared__ float Msk[64];

    short8 onesB;
#pragma unroll
    for (int e = 0; e < 8; ++e) onesB[e] = (short)0x3F80;   // bf16 1.0

    short8 qf[2][2];
#pragma unroll
    for (int i = 0; i < 2; ++i)
#pragma unroll
        for (int kk = 0; kk < 2; ++kk)
            qf[i][kk] = *(const short8*)&QKV[(tok0 + qt + w * 32 + i * 16 + lr) * LD
                                             + h * 64 + kk * 32 + g * 8];

    const int rsub = w * 8 + (lane >> 3);       // staging row 0..31 (plus p*32)
    const int slot = lane & 7;
    int wofs[2];                                 // swizzled LDS write offsets
#pragma unroll
    for (int p = 0; p < 2; ++p) {
        const int row = p * 32 + rsub;
        wofs[p] = row * 64 + ((slot ^ (row & 7)) << 3);
    }

    float m_[2] = {20.f, 20.f};     // stale-max init; P = 2^(x-20) stays normal
    f32x4 lacc[2] = {};             // row-sum acc (ones-MFMA), same layout as o_
    f32x4 o_[2][4] = {};

    ushort8v kreg[2], vreg[2];
    int mreg = 1;

    // ---- prologue: reg-load tile 0, write to LDS
#pragma unroll
    for (int p = 0; p < 2; ++p) {
        const int row = p * 32 + rsub;
        kreg[p] = *(const ushort8v*)&QKV[(tok0 + kvb0 + row) * LD + D_MODEL + h * 64 + slot * 8];
        vreg[p] = *(const ushort8v*)&Vt[((size_t)bh * 64 + row) * SEQ + kvb0 + slot * 8];
    }
    if (tid < 64) mreg = mask[b * SEQ + kvb0 + tid];
#pragma unroll
    for (int p = 0; p < 2; ++p) {
        *(ushort8v*)&Ks[wofs[p]] = kreg[p];
        *(ushort8v*)&Vs[wofs[p]] = vreg[p];
    }
    if (tid < 64) Msk[tid] = mreg ? 0.f : -1e9f;
    __syncthreads();

    const int NT = (SEQ / 2) / 64;   // 16
    for (int t = 0; t < NT; ++t) {
        // ---- issue next-tile loads EARLY (HBM latency hides under compute)
        if (t + 1 < NT) {
            const int kvn = kvb0 + (t + 1) * 64;
#pragma unroll
            for (int p = 0; p < 2; ++p) {
                const int row = p * 32 + rsub;
                kreg[p] = *(const ushort8v*)&QKV[(tok0 + kvn + row) * LD + D_MODEL + h * 64 + slot * 8];
                vreg[p] = *(const ushort8v*)&Vt[((size_t)bh * 64 + row) * SEQ + kvn + slot * 8];
            }
            if (tid < 64) mreg = mask[b * SEQ + kvn + tid];
        }

        // ---- QK^T (swapped): sacc[i][j][r] = S[kv=j*16+g*4+r][q=i*16+lr]
        f32x4 sacc[2][4] = {};
#pragma unroll
        for (int j = 0; j < 4; ++j) {
            short8 kf0 = *(const short8*)&Ks[(j * 16 + lr) * 64 + ((0 + g) ^ (lr & 7)) * 8];
            short8 kf1 = *(const short8*)&Ks[(j * 16 + lr) * 64 + ((4 + g) ^ (lr & 7)) * 8];
#pragma unroll
            for (int i = 0; i < 2; ++i) {
                sacc[i][j] = __builtin_amdgcn_mfma_f32_16x16x32_bf16(kf0, qf[i][0], sacc[i][j], 0, 0, 0);
                sacc[i][j] = __builtin_amdgcn_mfma_f32_16x16x32_bf16(kf1, qf[i][1], sacc[i][j], 0, 0, 0);
            }
        }

        float mb[4][4];
#pragma unroll
        for (int j = 0; j < 4; ++j) {
            f32x4 mrow = *(const f32x4*)&Msk[j * 16 + g * 4];
#pragma unroll
            for (int r = 0; r < 4; ++r) mb[j][r] = mrow[r];
        }

        // ---- softmax: exp with STALE m_ (no wait on cross-lane max)
        float tmv[2];
#pragma unroll
        for (int i = 0; i < 2; ++i) {
            float x[4][4];
            float tm = -1e30f;
#pragma unroll
            for (int j = 0; j < 4; ++j)
#pragma unroll
                for (int r = 0; r < 4; ++r) {
                    x[j][r] = fmaf(sacc[i][j][r], C1, mb[j][r]);
                    tm = fmaxf(tm, x[j][r]);
                }
            // exp path: independent of the shfl-max chain
#pragma unroll
            for (int j = 0; j < 4; ++j) {
                ushort4v pw;
#pragma unroll
                for (int r = 0; r < 4; ++r)
                    pw[r] = f2bf(exp2_fast(x[j][r] - m_[i]));
                *(ushort4v*)((char*)&Ps[w][0] + (i * 16 + lr) * 128
                             + ((j * 32 + g * 8) ^ ((lr & 7) << 4))) = pw;
            }
            // max path (off critical path)
            tm = fmaxf(tm, __shfl_xor(tm, 16));
            tm = fmaxf(tm, __shfl_xor(tm, 32));
            tmv[i] = tm;
        }

        // ---- PV + l: O += P@V ; l += P@ones (same C layout as O)
#pragma unroll
        for (int kk = 0; kk < 2; ++kk) {
            short8 pf[2];
#pragma unroll
            for (int i = 0; i < 2; ++i) {
                pf[i] = *(const short8*)&Ps[w][(i * 16 + lr) * 64 + ((kk * 4 + g) ^ (lr & 7)) * 8];
                lacc[i] = __builtin_amdgcn_mfma_f32_16x16x32_bf16(pf[i], onesB, lacc[i], 0, 0, 0);
            }
#pragma unroll
            for (int dj = 0; dj < 4; ++dj) {
                short8 vf = *(const short8*)&Vs[(dj * 16 + lr) * 64 + ((kk * 4 + g) ^ (lr & 7)) * 8];
#pragma unroll
                for (int i = 0; i < 2; ++i)
                    o_[i][dj] = __builtin_amdgcn_mfma_f32_16x16x32_bf16(pf[i], vf, o_[i][dj], 0, 0, 0);
            }
        }

        // ---- deferred rescale (rare): uniform post-scaling is exact
#pragma unroll
        for (int i = 0; i < 2; ++i) {
            if (__any(tmv[i] > m_[i] + 8.f)) {
                const float nm = fmaxf(m_[i], tmv[i]);
                const float sc = exp2_fast(m_[i] - nm);
                m_[i] = nm;
#pragma unroll
                for (int r = 0; r < 4; ++r) {
                    const float s_r = __shfl(sc, g * 4 + r);
                    lacc[i][r] *= s_r;
#pragma unroll
                    for (int dj = 0; dj < 4; ++dj) o_[i][dj][r] *= s_r;
                }
            }
        }

        __syncthreads();   // all reads of Ks/Vs/Msk done

        // ---- write staged regs -> LDS (vmcnt wait here, covered by compute)
        if (t + 1 < NT) {
#pragma unroll
            for (int p = 0; p < 2; ++p) {
                *(ushort8v*)&Ks[wofs[p]] = kreg[p];
                *(ushort8v*)&Vs[wofs[p]] = vreg[p];
            }
            if (tid < 64) Msk[tid] = mreg ? 0.f : -1e9f;
        }
        __syncthreads();   // writes visible
    }

    // ---- epilogue: write unnormalized O (bf16) + m + l (shuffle-free)
    const int rowbase = (sp * 32 + bh) * 2048;
#pragma unroll
    for (int i = 0; i < 2; ++i) {
#pragma unroll
        for (int r = 0; r < 4; ++r) {
            const int q = qt + w * 32 + i * 16 + g * 4 + r;
            unsigned short* op = Op + (size_t)(rowbase + q) * 64;
#pragma unroll
            for (int dj = 0; dj < 4; ++dj) op[dj * 16 + lr] = f2bf(o_[i][dj][r]);
        }
        if (g == 0) mA[rowbase + qt + w * 32 + i * 16 + lr] = m_[i];
        if (lr == 0) {
#pragma unroll
            for (int r = 0; r < 4; ++r)
                lA[rowbase + qt + w * 32 + i * 16 + g * 4 + r] = lacc[i][r];
        }
    }
}

// ---------------------------------------------------------------------------
// merge 2 attention splits (bf16 partials) -> bf16 ctx [tok][1024]
// ---------------------------------------------------------------------------
__global__ __launch_bounds__(256) void attn_merge_kernel(
    const unsigned short* __restrict__ Op, const float* __restrict__ mA,
    const float* __restrict__ lA, unsigned short* __restrict__ ctx)
{
    const int tid = threadIdx.x;
    const int row = blockIdx.x * 16 + (tid >> 4);   // bh*2048 + q, 0..65535
    const int d4 = (tid & 15) * 4;
    const int bh = row >> 11, q = row & 2047;
    const int b = bh >> 4, h = bh & 15;
    const float m0 = mA[row], m1 = mA[65536 + row];
    const float l0 = lA[row], l1 = lA[65536 + row];
    const float m = fmaxf(m0, m1);
    const float a0 = exp2_fast(m0 - m), a1 = exp2_fast(m1 - m);
    const float inv = 1.f / (l0 * a0 + l1 * a1);
    ushort4v O0 = *(const ushort4v*)&Op[(size_t)row * 64 + d4];
    ushort4v O1 = *(const ushort4v*)&Op[((size_t)65536 + row) * 64 + d4];
    ushort4v o;
#pragma unroll
    for (int e = 0; e < 4; ++e)
        o[e] = f2bf((bf2f(O0[e]) * a0 + bf2f(O1[e]) * a1) * inv);
    *(ushort4v*)&ctx[((size_t)(b * SEQ + q)) * D_MODEL + h * 64 + d4] = o;
}

// ---------------------------------------------------------------------------
// fused split-K reduce + residual + LayerNorm (f32 or bf16 partials)
// ---------------------------------------------------------------------------
__global__ __launch_bounds__(256) void reduce_ln_kernel(
    const void* __restrict__ P, int pbf, int nsplit, const float* __restrict__ bias,
    const float* __restrict__ X, const float* __restrict__ g,
    const float* __restrict__ be, float* __restrict__ out,
    unsigned short* __restrict__ outb)
{
    const int row = blockIdx.x, tid = threadIdx.x;
    __shared__ float red[4];
    const size_t MN = (size_t)NTOK * D_MODEL;
    const size_t base = (size_t)row * D_MODEL + tid * 4;

    f32x4 s = *(const f32x4*)(X + base);
    f32x4 bb = *(const f32x4*)(bias + tid * 4);
    s += bb;
    if (pbf) {
        const unsigned short* Pb = (const unsigned short*)P;
        for (int sp = 0; sp < nsplit; ++sp) {
            ushort4v pv = *(const ushort4v*)(Pb + sp * MN + base);
#pragma unroll
            for (int e = 0; e < 4; ++e) s[e] += bf2f(pv[e]);
        }
    } else {
        const float* Pf = (const float*)P;
        for (int sp = 0; sp < nsplit; ++sp)
            s += *(const f32x4*)(Pf + sp * MN + base);
    }

    float ls = s[0] + s[1] + s[2] + s[3];
#pragma unroll
    for (int o = 32; o > 0; o >>= 1) ls += __shfl_down(ls, o);
    if ((tid & 63) == 0) red[tid >> 6] = ls;
    __syncthreads();
    const float mu = (red[0] + red[1] + red[2] + red[3]) * (1.f / D_MODEL);
    __syncthreads();

    float d0 = s[0] - mu, d1 = s[1] - mu, d2 = s[2] - mu, d3 = s[3] - mu;
    float lv = d0 * d0 + d1 * d1 + d2 * d2 + d3 * d3;
#pragma unroll
    for (int o = 32; o > 0; o >>= 1) lv += __shfl_down(lv, o);
    if ((tid & 63) == 0) red[tid >> 6] = lv;
    __syncthreads();
    const float var = (red[0] + red[1] + red[2] + red[3]) * (1.f / D_MODEL);
    const float inv = rsqrtf(var + EPS);

    f32x4 gv = *(const f32x4*)(g + tid * 4);
    f32x4 bv = *(const f32x4*)(be + tid * 4);
    f32x4 o4 = {d0 * inv * gv[0] + bv[0], d1 * inv * gv[1] + bv[1],
                d2 * inv * gv[2] + bv[2], d3 * inv * gv[3] + bv[3]};
    *(f32x4*)(out + base) = o4;
    if (outb) {
        ushort4v ob = {f2bf(o4[0]), f2bf(o4[1]), f2bf(o4[2]), f2bf(o4[3])};
        *(ushort4v*)(outb + base) = ob;
    }
}

// ---------------------------------------------------------------------------
extern "C" void kernel_launch(void* const* d_in, const int* in_sizes, int n_in,
                              void* d_out, int out_size, void* d_ws, size_t ws_size,
                              hipStream_t stream) {
    const float* x      = (const float*)d_in[0];
    const int*   mask   = (const int*)  d_in[1];
    const float* wq_w   = (const float*)d_in[2];
    const float* wq_b   = (const float*)d_in[3];
    const float* wk_w   = (const float*)d_in[4];
    const float* wk_b   = (const float*)d_in[5];
    const float* wv_w   = (const float*)d_in[6];
    const float* wv_b   = (const float*)d_in[7];
    const float* wo_w   = (const float*)d_in[8];
    const float* wo_b   = (const float*)d_in[9];
    const float* ffn_w1 = (const float*)d_in[10];
    const float* ffn_b1 = (const float*)d_in[11];
    const float* ffn_w2 = (const float*)d_in[12];
    const float* ffn_b2 = (const float*)d_in[13];
    const float* ln1_g  = (const float*)d_in[14];
    const float* ln1_b  = (const float*)d_in[15];
    const float* ln2_g  = (const float*)d_in[16];
    const float* ln2_b  = (const float*)d_in[17];
    float* out = (float*)d_out;

    char* w = (char*)d_ws;
    const size_t MB = 1024 * 1024;
    // lifetime-audited layout (phases: A prep, B qkv, C vtrans, D attn,
    // Dm merge, E wo, F ln1, G ffn1, H ffn2, I ln2):
    unsigned short* actb    = (unsigned short*)(w);            // 0-8     A..B
    unsigned short* wqkvT   = (unsigned short*)(w + 8 * MB);   // 8-14    A..B
    float*          biasqkv = (float*)(w + 14 * MB);           // 14-16   A..B
    unsigned short* qkvb    = (unsigned short*)(w + 16 * MB);  // 16-40   B..D
    unsigned short* vt      = (unsigned short*)(w + 40 * MB);  // 40-48   C..D
    unsigned short* ctxb    = (unsigned short*)(w + 48 * MB);  // 48-56   Dm..E
    unsigned short* Opb     = (unsigned short*)(w + 56 * MB);  // 56-72   D..Dm (bf16)
    float*          mAb     = (float*)(w + 72 * MB);           // 72-72.5 D..Dm
    float*          lAb     = (float*)(w + 73 * MB);           // 73-73.5 D..Dm
    unsigned short* woT     = (unsigned short*)(w + 74 * MB);  // 74-76   A..E
    unsigned short* woPb    = (unsigned short*)(w);            // 0-16    E..F (2 bf16 splits)
    float*          Out1    = (float*)(w + 64 * MB);           // 64-80   F..I
    unsigned short* out1b   = (unsigned short*)(w + 40 * MB);  // 40-48   F..G
    unsigned short* fhb     = (unsigned short*)(w + 80 * MB);  // 80-112  G..H
    unsigned short* w2T     = (unsigned short*)(w + 112 * MB); // 112-120 A..H
    unsigned short* w1T     = (unsigned short*)(w + 120 * MB); // 120-128 A..G
    unsigned short* f2Pb    = (unsigned short*)(w);            // 0-32    H..I (4 bf16 splits)

    dim3 blk(256);

    // --- A: fused prep (6 transposes + bias concat + x cast), one launch
    prep_kernel<<<dim3(5132), blk, 0, stream>>>(
        wq_w, wk_w, wv_w, wo_w, ffn_w1, ffn_w2, wq_b, wk_b, wv_b, x,
        wqkvT, woT, w1T, w2T, biasqkv, actb);

    // --- B: merged QKV projection -> bf16 packed (256x256 pipelined)
    gemm256_kernel<<<dim3(192), dim3(512), 0, stream>>>(actb, wqkvT, biasqkv, nullptr, qkvb,
                                                        NTOK, 3072, 1024, 1024, 1, 0, 1);
    // --- C: V transpose
    vtrans_kernel<<<dim3(SEQ / 64, N_HEADS, BATCH), blk, 0, stream>>>(qkvb, vt);

    // --- D: MFMA flash attention, split-S=2 (reg-staged, 4 blocks/CU), merge
    attn_mfma_kernel<<<dim3(SEQ / 128, N_HEADS, BATCH * 2), blk, 0, stream>>>(
        qkvb, vt, mask, Opb, mAb, lAb);
    attn_merge_kernel<<<dim3((BATCH * N_HEADS * SEQ) / 16), blk, 0, stream>>>(
        Opb, mAb, lAb, ctxb);

    // --- E: output projection, split-K=2 -> bf16 partials; LN1 fused reduce
    gemm_bt_kernel<<<dim3(8, 32, 2), blk, 0, stream>>>(ctxb, woT, nullptr, nullptr, woPb,
                                                       NTOK, 1024, 1024, 512, 0, 1);
    reduce_ln_kernel<<<dim3(NTOK), blk, 0, stream>>>(woPb, 1, 2, wo_b, x, ln1_g, ln1_b,
                                                     Out1, out1b);
    // --- G: FFN1 (256x256 pipelined)
    gemm256_kernel<<<dim3(256), dim3(512), 0, stream>>>(out1b, w1T, ffn_b1, nullptr, fhb,
                                                        NTOK, D_FF, 1024, 1024, 1, 1, 1);
    // --- H: FFN2, split-K=4 -> bf16 partials
    gemm256_kernel<<<dim3(256), dim3(512), 0, stream>>>(fhb, w2T, nullptr, nullptr, f2Pb,
                                                        NTOK, 1024, 4096, 1024, 4, 0, 1);
    // --- I: LN2 fused with ffn2-reduce -> out
    reduce_ln_kernel<<<dim3(NTOK), blk, 0, stream>>>(f2Pb, 1, 4, ffn_b2, Out1, ln2_g, ln2_b,
                                                     out, nullptr);
}

// Round 13
// 248.168 us; speedup vs baseline: 1.2762x; 1.2762x over previous
//
#include <hip/hip_runtime.h>
#include <hip/hip_bf16.h>

#define D_MODEL 1024
#define N_HEADS 16
#define DEPTH   64
#define D_FF    4096
#define BATCH   2
#define SEQ     2048
#define NTOK    (BATCH * SEQ)   // 4096
#define EPS     1e-5f

typedef __attribute__((ext_vector_type(8))) short short8;
typedef __attribute__((ext_vector_type(4))) float f32x4;
typedef __attribute__((ext_vector_type(4))) unsigned short ushort4v;
typedef __attribute__((ext_vector_type(8))) unsigned short ushort8v;

__device__ __forceinline__ unsigned short f2bf(float f) {
    union { __hip_bfloat16 h; unsigned short u; } cv;
    cv.h = __float2bfloat16(f);   // RNE
    return cv.u;
}

__device__ __forceinline__ float bf2f(unsigned short u) {
    union { float f; unsigned int i; } c;
    c.i = (unsigned int)u << 16;
    return c.f;
}

__device__ __forceinline__ float exp2_fast(float x) {
    float r;
    asm("v_exp_f32 %0, %1" : "=v"(r) : "v"(x));
    return r;
}

__device__ __forceinline__ void gload16(const unsigned short* g, unsigned short* lds) {
    __builtin_amdgcn_global_load_lds(
        (const __attribute__((address_space(1))) void*)g,
        (__attribute__((address_space(3))) void*)lds, 16, 0, 0);
}

// ---------------------------------------------------------------------------
// fused prep: all weight transposes (f32->bf16), bias concat, x cast.
// ---------------------------------------------------------------------------
__device__ __forceinline__ void tc_tile(
    const float* __restrict__ W, unsigned short* __restrict__ WT,
    int K, int N, int bn64, int bk64, int tid, float (*t)[65])
{
    const int bk = bk64 * 64, bn = bn64 * 64;
    const int c4 = tid & 15, r0 = tid >> 4;
#pragma unroll
    for (int i = 0; i < 4; ++i) {
        int k = r0 + i * 16;
        f32x4 v = *(const f32x4*)&W[(size_t)(bk + k) * N + bn + c4 * 4];
#pragma unroll
        for (int jj = 0; jj < 4; ++jj) t[k][c4 * 4 + jj] = v[jj];
    }
    __syncthreads();
#pragma unroll
    for (int i = 0; i < 4; ++i) {
        int n = r0 + i * 16;
        ushort4v o;
#pragma unroll
        for (int jj = 0; jj < 4; ++jj) o[jj] = f2bf(t[c4 * 4 + jj][n]);
        *(ushort4v*)&WT[(size_t)(bn + n) * K + bk + c4 * 4] = o;
    }
}

__global__ __launch_bounds__(256) void prep_kernel(
    const float* __restrict__ wq_w, const float* __restrict__ wk_w,
    const float* __restrict__ wv_w, const float* __restrict__ wo_w,
    const float* __restrict__ ffn_w1, const float* __restrict__ ffn_w2,
    const float* __restrict__ wq_b, const float* __restrict__ wk_b,
    const float* __restrict__ wv_b, const float* __restrict__ x,
    unsigned short* __restrict__ wqkvT, unsigned short* __restrict__ woT,
    unsigned short* __restrict__ w1T, unsigned short* __restrict__ w2T,
    float* __restrict__ biasqkv, unsigned short* __restrict__ actb)
{
    __shared__ float t[64][65];
    const int idx = blockIdx.x, tid = threadIdx.x;

    if (idx < 1024) {
        const int wsel = idx >> 8, rel = idx & 255;
        const float* W = (wsel == 0) ? wq_w : (wsel == 1) ? wk_w : (wsel == 2) ? wv_w : wo_w;
        unsigned short* WT = (wsel == 3) ? woT : (wqkvT + (size_t)wsel * 1024 * 1024);
        tc_tile(W, WT, 1024, 1024, rel & 15, rel >> 4, tid, t);
    } else if (idx < 2048) {
        const int rel = idx - 1024;
        tc_tile(ffn_w1, w1T, 1024, 4096, rel & 63, rel >> 6, tid, t);
    } else if (idx < 3072) {
        const int rel = idx - 2048;
        tc_tile(ffn_w2, w2T, 4096, 1024, rel & 15, rel >> 4, tid, t);
    } else if (idx < 3084) {
        const int i = (idx - 3072) * 256 + tid;
        if (i < 1024) biasqkv[i] = wq_b[i];
        else if (i < 2048) biasqkv[i] = wk_b[i - 1024];
        else if (i < 3072) biasqkv[i] = wv_b[i - 2048];
    } else {
        const int i = ((idx - 3084) * 256 + tid) * 8;
        f32x4 a = *(const f32x4*)&x[i];
        f32x4 b = *(const f32x4*)&x[i + 4];
        ushort8v o;
        o[0] = f2bf(a[0]); o[1] = f2bf(a[1]); o[2] = f2bf(a[2]); o[3] = f2bf(a[3]);
        o[4] = f2bf(b[0]); o[5] = f2bf(b[1]); o[6] = f2bf(b[2]); o[7] = f2bf(b[3]);
        *(ushort8v*)&actb[i] = o;
    }
}

// ---------------------------------------------------------------------------
// V^T extraction: QKV bf16 [tok][3072] (V at col 2048+) -> Vt[bh][64][2048]
// ---------------------------------------------------------------------------
__global__ __launch_bounds__(256) void vtrans_kernel(
    const unsigned short* __restrict__ QKV, unsigned short* __restrict__ Vt)
{
    __shared__ unsigned short T[64][72];
    const int st = blockIdx.x * 64;
    const int h = blockIdx.y, b = blockIdx.z;
    const int tid = threadIdx.x;
    const size_t tok0 = (size_t)b * SEQ;
    const int LD = 3 * D_MODEL;
    const int r = tid >> 3, c8 = (tid & 7) * 8;
#pragma unroll
    for (int p = 0; p < 2; ++p) {
        int row = p * 32 + r;
        *(ushort8v*)&T[row][c8] =
            *(const ushort8v*)&QKV[(tok0 + st + row) * LD + 2048 + h * 64 + c8];
    }
    __syncthreads();
    const int bh = b * N_HEADS + h;
#pragma unroll
    for (int p = 0; p < 2; ++p) {
        int d = p * 32 + r;
        ushort8v o;
#pragma unroll
        for (int e = 0; e < 8; ++e) o[e] = T[c8 + e][d];
        *(ushort8v*)&Vt[((size_t)bh * 64 + d) * SEQ + st + c8] = o;
    }
}

// ---------------------------------------------------------------------------
// 256x256 pipelined bf16 MFMA GEMM with optional split-K.
// ---------------------------------------------------------------------------
__global__ __launch_bounds__(512, 2) void gemm256_kernel(
    const unsigned short* __restrict__ A, const unsigned short* __restrict__ BT,
    const float* __restrict__ bias, float* __restrict__ C,
    unsigned short* __restrict__ Cb,
    int M, int N, int lda, int kLen, int ksplit, int relu, int out_bf)
{
    __shared__ unsigned short As[2][256 * 64];
    __shared__ unsigned short Bs[2][256 * 64];
    const int tid = threadIdx.x;
    const int lane = tid & 63, w = tid >> 6;
    const int wr = w >> 2, wc = w & 3;
    const int lr = lane & 15, g = lane >> 4;

    // XCD-aware block swizzle (bijective when nwg % 8 == 0)
    const int nwg = gridDim.x;
    int wg = blockIdx.x;
    if ((nwg & 7) == 0) wg = (wg & 7) * (nwg >> 3) + (wg >> 3);
    if (ksplit > 1) {
        const int ntile = nwg / ksplit;
        const int split = wg / ntile;
        wg = wg % ntile;
        A  += (size_t)split * kLen;
        BT += (size_t)split * kLen;
        C  += (size_t)split * M * N;
        Cb += (size_t)split * M * N;
    }
    const int gx = N >> 8;
    const int bm = (wg / gx) * 256, bn = (wg % gx) * 256;

    const int srow = (w << 3) + (lane >> 3);
    const int scol = ((lane & 7) ^ (lane >> 3)) << 3;
    const int ldst = (w << 9);

#define STG(P, Xs, bufi, hf, rb, k0)                                            \
    {                                                                            \
        gload16(P + (size_t)((rb) + (hf) * 128 + srow) * lda + (k0) + scol,      \
                &Xs[bufi][(hf) * 8192 + ldst]);                                  \
        gload16(P + (size_t)((rb) + (hf) * 128 + 64 + srow) * lda + (k0) + scol, \
                &Xs[bufi][(hf) * 8192 + 4096 + ldst]);                           \
    }

    const int NS = kLen >> 6;
    f32x4 acc[8][4] = {};

    STG(A,  As, 0, 0, bm, 0); STG(A,  As, 0, 1, bm, 0);
    STG(BT, Bs, 0, 0, bn, 0); STG(BT, Bs, 0, 1, bn, 0);
    if (NS > 1) { STG(BT, Bs, 1, 0, bn, 64); STG(BT, Bs, 1, 1, bn, 64); }
    asm volatile("s_waitcnt vmcnt(4)" ::: "memory");
    __builtin_amdgcn_s_barrier();
    asm volatile("" ::: "memory");

    int buf = 0;
    short8 af[4][2], b0[2][2], b1[2][2];
    for (int s = 0; s < NS; ++s) {
        const int kn1 = (s + 1) << 6, kn2 = (s + 2) << 6;

        // ---- phase 1
#pragma unroll
        for (int i = 0; i < 4; ++i)
#pragma unroll
            for (int kk = 0; kk < 2; ++kk)
                af[i][kk] = *(const short8*)&As[buf][(wr * 128 + i * 16 + lr) * 64
                                                    + (((kk * 4 + g) ^ (lr & 7)) << 3)];
#pragma unroll
        for (int j = 0; j < 2; ++j)
#pragma unroll
            for (int kk = 0; kk < 2; ++kk)
                b0[j][kk] = *(const short8*)&Bs[buf][(wc * 64 + j * 16 + lr) * 64
                                                    + (((kk * 4 + g) ^ (lr & 7)) << 3)];
        if (s + 1 < NS) STG(A, As, buf ^ 1, 0, bm, kn1);
        asm volatile("" ::: "memory");
        __builtin_amdgcn_s_barrier();
        asm volatile("" ::: "memory");
        __builtin_amdgcn_s_setprio(1);
#pragma unroll
        for (int i = 0; i < 4; ++i)
#pragma unroll
            for (int j = 0; j < 2; ++j) {
                acc[i][j] = __builtin_amdgcn_mfma_f32_16x16x32_bf16(af[i][0], b0[j][0], acc[i][j], 0, 0, 0);
                acc[i][j] = __builtin_amdgcn_mfma_f32_16x16x32_bf16(af[i][1], b0[j][1], acc[i][j], 0, 0, 0);
            }
        __builtin_amdgcn_s_setprio(0);
        asm volatile("" ::: "memory");
        __builtin_amdgcn_s_barrier();
        asm volatile("" ::: "memory");

        // ---- phase 2
#pragma unroll
        for (int j = 0; j < 2; ++j)
#pragma unroll
            for (int kk = 0; kk < 2; ++kk)
                b1[j][kk] = *(const short8*)&Bs[buf][(wc * 64 + (j + 2) * 16 + lr) * 64
                                                    + (((kk * 4 + g) ^ (lr & 7)) << 3)];
        if (s + 1 < NS) STG(A, As, buf ^ 1, 1, bm, kn1);
        asm volatile("" ::: "memory");
        __builtin_amdgcn_s_barrier();
        asm volatile("" ::: "memory");
        __builtin_amdgcn_s_setprio(1);
#pragma unroll
        for (int i = 0; i < 4; ++i)
#pragma unroll
            for (int j = 0; j < 2; ++j) {
                acc[i][j + 2] = __builtin_amdgcn_mfma_f32_16x16x32_bf16(af[i][0], b1[j][0], acc[i][j + 2], 0, 0, 0);
                acc[i][j + 2] = __builtin_amdgcn_mfma_f32_16x16x32_bf16(af[i][1], b1[j][1], acc[i][j + 2], 0, 0, 0);
            }
        __builtin_amdgcn_s_setprio(0);
        asm volatile("" ::: "memory");
        __builtin_amdgcn_s_barrier();
        asm volatile("" ::: "memory");

        // ---- phase 3
#pragma unroll
        for (int i = 0; i < 4; ++i)
#pragma unroll
            for (int kk = 0; kk < 2; ++kk)
                af[i][kk] = *(const short8*)&As[buf][(wr * 128 + 64 + i * 16 + lr) * 64
                                                    + (((kk * 4 + g) ^ (lr & 7)) << 3)];
        if (s + 2 < NS) STG(BT, Bs, buf, 0, bn, kn2);
        asm volatile("" ::: "memory");
        __builtin_amdgcn_s_barrier();
        asm volatile("" ::: "memory");
        __builtin_amdgcn_s_setprio(1);
#pragma unroll
        for (int i = 0; i < 4; ++i)
#pragma unroll
            for (int j = 0; j < 2; ++j) {
                acc[i + 4][j] = __builtin_amdgcn_mfma_f32_16x16x32_bf16(af[i][0], b0[j][0], acc[i + 4][j], 0, 0, 0);
                acc[i + 4][j] = __builtin_amdgcn_mfma_f32_16x16x32_bf16(af[i][1], b0[j][1], acc[i + 4][j], 0, 0, 0);
            }
        __builtin_amdgcn_s_setprio(0);
        asm volatile("" ::: "memory");
        __builtin_amdgcn_s_barrier();
        asm volatile("" ::: "memory");

        // ---- phase 4
        if (s + 2 < NS) STG(BT, Bs, buf, 1, bn, kn2);
        asm volatile("" ::: "memory");
        __builtin_amdgcn_s_barrier();
        asm volatile("" ::: "memory");
        __builtin_amdgcn_s_setprio(1);
#pragma unroll
        for (int i = 0; i < 4; ++i)
#pragma unroll
            for (int j = 0; j < 2; ++j) {
                acc[i + 4][j + 2] = __builtin_amdgcn_mfma_f32_16x16x32_bf16(af[i][0], b1[j][0], acc[i + 4][j + 2], 0, 0, 0);
                acc[i + 4][j + 2] = __builtin_amdgcn_mfma_f32_16x16x32_bf16(af[i][1], b1[j][1], acc[i + 4][j + 2], 0, 0, 0);
            }
        __builtin_amdgcn_s_setprio(0);
        asm volatile("s_waitcnt vmcnt(4)" ::: "memory");
        __builtin_amdgcn_s_barrier();
        asm volatile("" ::: "memory");

        buf ^= 1;
    }
#undef STG

#pragma unroll
    for (int i = 0; i < 8; ++i)
#pragma unroll
        for (int j = 0; j < 4; ++j) {
            const int col = bn + wc * 64 + j * 16 + lr;
            const float bv = bias ? bias[col] : 0.f;
#pragma unroll
            for (int r = 0; r < 4; ++r) {
                const int row = bm + wr * 128 + i * 16 + g * 4 + r;
                float v = acc[i][j][r] + bv;
                if (relu) v = fmaxf(v, 0.f);
                if (out_bf) Cb[(size_t)row * N + col] = f2bf(v);
                else        C [(size_t)row * N + col] = v;
            }
        }
}

// ---------------------------------------------------------------------------
// bf16 MFMA GEMM (m97 structure), 128x128 tile, optional split-K via blockIdx.z
// ---------------------------------------------------------------------------
__global__ __launch_bounds__(256) void gemm_bt_kernel(
    const unsigned short* __restrict__ A, const unsigned short* __restrict__ BT,
    const float* __restrict__ bias, float* __restrict__ C,
    unsigned short* __restrict__ Cb,
    int M, int N, int lda, int kLen, int relu, int out_bf)
{
    __shared__ unsigned short As[128 * 64];
    __shared__ unsigned short Bs[128 * 64];
    const int tid = threadIdx.x;
    const int lane = tid & 63, wv = tid >> 6;
    const int wr = wv >> 1, wc = wv & 1;
    const int bm = blockIdx.y * 128, bn = blockIdx.x * 128;
    const int kbase = blockIdx.z * kLen;
    const int lr = lane & 15, lk = (lane >> 4) << 3;

    C  += (size_t)blockIdx.z * M * N;
    Cb += (size_t)blockIdx.z * M * N;

    f32x4 acc[4][4] = {};

    for (int kt = 0; kt < kLen; kt += 64) {
#pragma unroll
        for (int c = 0; c < 4; ++c) {
            int e = c * 2048 + tid * 8;
            int row = e >> 6, k = e & 63;
            gload16(A  + (size_t)(bm + row) * lda + kbase + kt + k, As + c * 2048 + wv * 512);
            gload16(BT + (size_t)(bn + row) * lda + kbase + kt + k, Bs + c * 2048 + wv * 512);
        }
        __syncthreads();
#pragma unroll
        for (int kk = 0; kk < 2; ++kk) {
            short8 af[4], bfr[4];
#pragma unroll
            for (int i = 0; i < 4; ++i) {
                af[i]  = *(const short8*)&As[(wr * 64 + i * 16 + lr) * 64 + kk * 32 + lk];
                bfr[i] = *(const short8*)&Bs[(wc * 64 + i * 16 + lr) * 64 + kk * 32 + lk];
            }
#pragma unroll
            for (int i = 0; i < 4; ++i)
#pragma unroll
                for (int j = 0; j < 4; ++j)
                    acc[i][j] = __builtin_amdgcn_mfma_f32_16x16x32_bf16(
                        af[i], bfr[j], acc[i][j], 0, 0, 0);
        }
        __syncthreads();
    }

    const int r0 = bm + wr * 64, c0 = bn + wc * 64;
    const int rq = (lane >> 4) * 4;
#pragma unroll
    for (int i = 0; i < 4; ++i)
#pragma unroll
        for (int j = 0; j < 4; ++j) {
            int col = c0 + j * 16 + lr;
            float bv = bias ? bias[col] : 0.f;
#pragma unroll
            for (int r = 0; r < 4; ++r) {
                int row = r0 + i * 16 + rq + r;
                float v = acc[i][j][r] + bv;
                if (relu) v = fmaxf(v, 0.f);
                if (out_bf) Cb[(size_t)row * N + col] = f2bf(v);
                else        C [(size_t)row * N + col] = v;
            }
        }
}

// ---------------------------------------------------------------------------
// MFMA flash attention, split-S=2. 4 waves x 32 q (block = 128 q), KVBLK=64.
// (R10/R11 proven version: gload_lds staging, double-buffered K/V.)
// Deferred-max online softmax: exp uses stale m_ (init 20); rescale (rare)
// after PV. Row-sum l via ones-matrix MFMA. Outputs unnormalized O (bf16)
// + m + l per q-row.
// ---------------------------------------------------------------------------
__global__ __launch_bounds__(256, 3) void attn_mfma_kernel(
    const unsigned short* __restrict__ QKV,
    const unsigned short* __restrict__ Vt,
    const int* __restrict__ mask,
    unsigned short* __restrict__ Op, float* __restrict__ mA, float* __restrict__ lA)
{
    const int tid = threadIdx.x;
    const int lane = tid & 63, w = tid >> 6;
    const int lr = lane & 15, g = lane >> 4;   // g in 0..3
    const int qt = blockIdx.x * 128;
    const int h = blockIdx.y;
    const int b = blockIdx.z >> 1, sp = blockIdx.z & 1;
    const int bh = b * N_HEADS + h;
    const size_t tok0 = (size_t)b * SEQ;
    const int kvb0 = sp * (SEQ / 2);
    const int LD = 3 * D_MODEL;
    const float C1 = 0.18033688f;   // 0.125 * log2(e)

    __shared__ unsigned short Ks[2][64 * 64];   // [kv][d], 16B-slot swizzled
    __shared__ unsigned short Vs[2][64 * 64];   // [d][kv], 16B-slot swizzled
    __shared__ unsigned short Ps[4][32 * 64];   // per-wave P [q][kv], swizzled
    __shared__ float Msk[2][64];

    short8 onesB;
#pragma unroll
    for (int e = 0; e < 8; ++e) onesB[e] = (short)0x3F80;   // bf16 1.0

    short8 qf[2][2];
#pragma unroll
    for (int i = 0; i < 2; ++i)
#pragma unroll
        for (int kk = 0; kk < 2; ++kk)
            qf[i][kk] = *(const short8*)&QKV[(tok0 + qt + w * 32 + i * 16 + lr) * LD
                                             + h * 64 + kk * 32 + g * 8];

    const int rsub = w * 8 + (lane >> 3);
    const int slot = lane & 7;

    float m_[2] = {20.f, 20.f};     // stale-max init; P = 2^(x-20) stays normal
    f32x4 lacc[2] = {};             // row-sum acc (ones-MFMA), same layout as o_
    f32x4 o_[2][4] = {};

    {
#pragma unroll
        for (int p = 0; p < 2; ++p) {
            const int row = p * 32 + rsub;
            const int ss = slot ^ (row & 7);
            gload16(QKV + (tok0 + kvb0 + row) * LD + D_MODEL + h * 64 + ss * 8,
                    &Ks[0][(p * 32 + w * 8) * 64]);
            gload16(Vt + ((size_t)bh * 64 + row) * SEQ + kvb0 + ss * 8,
                    &Vs[0][(p * 32 + w * 8) * 64]);
        }
        if (tid < 64) Msk[0][tid] = mask[b * SEQ + kvb0 + tid] ? 0.f : -1e9f;
    }
    __syncthreads();

    const int NT = (SEQ / 2) / 64;   // 16
    int buf = 0;
    for (int t = 0; t < NT; ++t) {
        if (t + 1 < NT) {
            const int nb = buf ^ 1;
            const int kvn = kvb0 + (t + 1) * 64;
#pragma unroll
            for (int p = 0; p < 2; ++p) {
                const int row = p * 32 + rsub;
                const int ss = slot ^ (row & 7);
                gload16(QKV + (tok0 + kvn + row) * LD + D_MODEL + h * 64 + ss * 8,
                        &Ks[nb][(p * 32 + w * 8) * 64]);
                gload16(Vt + ((size_t)bh * 64 + row) * SEQ + kvn + ss * 8,
                        &Vs[nb][(p * 32 + w * 8) * 64]);
            }
            if (tid < 64) Msk[nb][tid] = mask[b * SEQ + kvn + tid] ? 0.f : -1e9f;
        }

        // ---- QK^T (swapped): sacc[i][j][r] = S[kv=j*16+g*4+r][q=i*16+lr]
        f32x4 sacc[2][4] = {};
#pragma unroll
        for (int j = 0; j < 4; ++j) {
            short8 kf0 = *(const short8*)&Ks[buf][(j * 16 + lr) * 64 + ((0 + g) ^ (lr & 7)) * 8];
            short8 kf1 = *(const short8*)&Ks[buf][(j * 16 + lr) * 64 + ((4 + g) ^ (lr & 7)) * 8];
#pragma unroll
            for (int i = 0; i < 2; ++i) {
                sacc[i][j] = __builtin_amdgcn_mfma_f32_16x16x32_bf16(kf0, qf[i][0], sacc[i][j], 0, 0, 0);
                sacc[i][j] = __builtin_amdgcn_mfma_f32_16x16x32_bf16(kf1, qf[i][1], sacc[i][j], 0, 0, 0);
            }
        }

        float mb[4][4];
#pragma unroll
        for (int j = 0; j < 4; ++j) {
            f32x4 mrow = *(const f32x4*)&Msk[buf][j * 16 + g * 4];
#pragma unroll
            for (int r = 0; r < 4; ++r) mb[j][r] = mrow[r];
        }

        // ---- softmax: exp with STALE m_ (no wait on cross-lane max)
        float tmv[2];
#pragma unroll
        for (int i = 0; i < 2; ++i) {
            float x[4][4];
            float tm = -1e30f;
#pragma unroll
            for (int j = 0; j < 4; ++j)
#pragma unroll
                for (int r = 0; r < 4; ++r) {
                    x[j][r] = fmaf(sacc[i][j][r], C1, mb[j][r]);
                    tm = fmaxf(tm, x[j][r]);
                }
            // exp path: independent of the shfl-max chain
#pragma unroll
            for (int j = 0; j < 4; ++j) {
                ushort4v pw;
#pragma unroll
                for (int r = 0; r < 4; ++r)
                    pw[r] = f2bf(exp2_fast(x[j][r] - m_[i]));
                *(ushort4v*)((char*)&Ps[w][0] + (i * 16 + lr) * 128
                             + ((j * 32 + g * 8) ^ ((lr & 7) << 4))) = pw;
            }
            // max path (off critical path)
            tm = fmaxf(tm, __shfl_xor(tm, 16));
            tm = fmaxf(tm, __shfl_xor(tm, 32));
            tmv[i] = tm;
        }

        // ---- PV + l: O += P@V ; l += P@ones (same C layout as O)
#pragma unroll
        for (int kk = 0; kk < 2; ++kk) {
            short8 pf[2];
#pragma unroll
            for (int i = 0; i < 2; ++i) {
                pf[i] = *(const short8*)&Ps[w][(i * 16 + lr) * 64 + ((kk * 4 + g) ^ (lr & 7)) * 8];
                lacc[i] = __builtin_amdgcn_mfma_f32_16x16x32_bf16(pf[i], onesB, lacc[i], 0, 0, 0);
            }
#pragma unroll
            for (int dj = 0; dj < 4; ++dj) {
                short8 vf = *(const short8*)&Vs[buf][(dj * 16 + lr) * 64 + ((kk * 4 + g) ^ (lr & 7)) * 8];
#pragma unroll
                for (int i = 0; i < 2; ++i)
                    o_[i][dj] = __builtin_amdgcn_mfma_f32_16x16x32_bf16(pf[i], vf, o_[i][dj], 0, 0, 0);
            }
        }

        // ---- deferred rescale (rare): uniform post-scaling is exact
#pragma unroll
        for (int i = 0; i < 2; ++i) {
            if (__any(tmv[i] > m_[i] + 8.f)) {
                const float nm = fmaxf(m_[i], tmv[i]);
                const float sc = exp2_fast(m_[i] - nm);
                m_[i] = nm;
#pragma unroll
                for (int r = 0; r < 4; ++r) {
                    const float s_r = __shfl(sc, g * 4 + r);
                    lacc[i][r] *= s_r;
#pragma unroll
                    for (int dj = 0; dj < 4; ++dj) o_[i][dj][r] *= s_r;
                }
            }
        }

        __syncthreads();   // drains gloads (vmcnt) + all LDS reads of buf
        buf ^= 1;
    }

    // ---- epilogue: write unnormalized O (bf16) + m + l (shuffle-free)
    const int rowbase = (sp * 32 + bh) * 2048;
#pragma unroll
    for (int i = 0; i < 2; ++i) {
#pragma unroll
        for (int r = 0; r < 4; ++r) {
            const int q = qt + w * 32 + i * 16 + g * 4 + r;
            unsigned short* op = Op + (size_t)(rowbase + q) * 64;
#pragma unroll
            for (int dj = 0; dj < 4; ++dj) op[dj * 16 + lr] = f2bf(o_[i][dj][r]);
        }
        if (g == 0) mA[rowbase + qt + w * 32 + i * 16 + lr] = m_[i];
        if (lr == 0) {
#pragma unroll
            for (int r = 0; r < 4; ++r)
                lA[rowbase + qt + w * 32 + i * 16 + g * 4 + r] = lacc[i][r];
        }
    }
}

// ---------------------------------------------------------------------------
// merge 2 attention splits (bf16 partials) -> bf16 ctx [tok][1024]
// ---------------------------------------------------------------------------
__global__ __launch_bounds__(256) void attn_merge_kernel(
    const unsigned short* __restrict__ Op, const float* __restrict__ mA,
    const float* __restrict__ lA, unsigned short* __restrict__ ctx)
{
    const int tid = threadIdx.x;
    const int row = blockIdx.x * 16 + (tid >> 4);   // bh*2048 + q, 0..65535
    const int d4 = (tid & 15) * 4;
    const int bh = row >> 11, q = row & 2047;
    const int b = bh >> 4, h = bh & 15;
    const float m0 = mA[row], m1 = mA[65536 + row];
    const float l0 = lA[row], l1 = lA[65536 + row];
    const float m = fmaxf(m0, m1);
    const float a0 = exp2_fast(m0 - m), a1 = exp2_fast(m1 - m);
    const float inv = 1.f / (l0 * a0 + l1 * a1);
    ushort4v O0 = *(const ushort4v*)&Op[(size_t)row * 64 + d4];
    ushort4v O1 = *(const ushort4v*)&Op[((size_t)65536 + row) * 64 + d4];
    ushort4v o;
#pragma unroll
    for (int e = 0; e < 4; ++e)
        o[e] = f2bf((bf2f(O0[e]) * a0 + bf2f(O1[e]) * a1) * inv);
    *(ushort4v*)&ctx[((size_t)(b * SEQ + q)) * D_MODEL + h * 64 + d4] = o;
}

// ---------------------------------------------------------------------------
// fused split-K reduce + residual + LayerNorm (f32 or bf16 partials)
// ---------------------------------------------------------------------------
__global__ __launch_bounds__(256) void reduce_ln_kernel(
    const void* __restrict__ P, int pbf, int nsplit, const float* __restrict__ bias,
    const float* __restrict__ X, const float* __restrict__ g,
    const float* __restrict__ be, float* __restrict__ out,
    unsigned short* __restrict__ outb)
{
    const int row = blockIdx.x, tid = threadIdx.x;
    __shared__ float red[4];
    const size_t MN = (size_t)NTOK * D_MODEL;
    const size_t base = (size_t)row * D_MODEL + tid * 4;

    f32x4 s = *(const f32x4*)(X + base);
    f32x4 bb = *(const f32x4*)(bias + tid * 4);
    s += bb;
    if (pbf) {
        const unsigned short* Pb = (const unsigned short*)P;
        for (int sp = 0; sp < nsplit; ++sp) {
            ushort4v pv = *(const ushort4v*)(Pb + sp * MN + base);
#pragma unroll
            for (int e = 0; e < 4; ++e) s[e] += bf2f(pv[e]);
        }
    } else {
        const float* Pf = (const float*)P;
        for (int sp = 0; sp < nsplit; ++sp)
            s += *(const f32x4*)(Pf + sp * MN + base);
    }

    float ls = s[0] + s[1] + s[2] + s[3];
#pragma unroll
    for (int o = 32; o > 0; o >>= 1) ls += __shfl_down(ls, o);
    if ((tid & 63) == 0) red[tid >> 6] = ls;
    __syncthreads();
    const float mu = (red[0] + red[1] + red[2] + red[3]) * (1.f / D_MODEL);
    __syncthreads();

    float d0 = s[0] - mu, d1 = s[1] - mu, d2 = s[2] - mu, d3 = s[3] - mu;
    float lv = d0 * d0 + d1 * d1 + d2 * d2 + d3 * d3;
#pragma unroll
    for (int o = 32; o > 0; o >>= 1) lv += __shfl_down(lv, o);
    if ((tid & 63) == 0) red[tid >> 6] = lv;
    __syncthreads();
    const float var = (red[0] + red[1] + red[2] + red[3]) * (1.f / D_MODEL);
    const float inv = rsqrtf(var + EPS);

    f32x4 gv = *(const f32x4*)(g + tid * 4);
    f32x4 bv = *(const f32x4*)(be + tid * 4);
    f32x4 o4 = {d0 * inv * gv[0] + bv[0], d1 * inv * gv[1] + bv[1],
                d2 * inv * gv[2] + bv[2], d3 * inv * gv[3] + bv[3]};
    *(f32x4*)(out + base) = o4;
    if (outb) {
        ushort4v ob = {f2bf(o4[0]), f2bf(o4[1]), f2bf(o4[2]), f2bf(o4[3])};
        *(ushort4v*)(outb + base) = ob;
    }
}

// ---------------------------------------------------------------------------
extern "C" void kernel_launch(void* const* d_in, const int* in_sizes, int n_in,
                              void* d_out, int out_size, void* d_ws, size_t ws_size,
                              hipStream_t stream) {
    const float* x      = (const float*)d_in[0];
    const int*   mask   = (const int*)  d_in[1];
    const float* wq_w   = (const float*)d_in[2];
    const float* wq_b   = (const float*)d_in[3];
    const float* wk_w   = (const float*)d_in[4];
    const float* wk_b   = (const float*)d_in[5];
    const float* wv_w   = (const float*)d_in[6];
    const float* wv_b   = (const float*)d_in[7];
    const float* wo_w   = (const float*)d_in[8];
    const float* wo_b   = (const float*)d_in[9];
    const float* ffn_w1 = (const float*)d_in[10];
    const float* ffn_b1 = (const float*)d_in[11];
    const float* ffn_w2 = (const float*)d_in[12];
    const float* ffn_b2 = (const float*)d_in[13];
    const float* ln1_g  = (const float*)d_in[14];
    const float* ln1_b  = (const float*)d_in[15];
    const float* ln2_g  = (const float*)d_in[16];
    const float* ln2_b  = (const float*)d_in[17];
    float* out = (float*)d_out;

    char* w = (char*)d_ws;
    const size_t MB = 1024 * 1024;
    // lifetime-audited layout (phases: A prep, B qkv, C vtrans, D attn,
    // Dm merge, E wo, F ln1, G ffn1, H ffn2, I ln2):
    unsigned short* actb    = (unsigned short*)(w);            // 0-8     A..B
    unsigned short* wqkvT   = (unsigned short*)(w + 8 * MB);   // 8-14    A..B
    float*          biasqkv = (float*)(w + 14 * MB);           // 14-16   A..B
    unsigned short* qkvb    = (unsigned short*)(w + 16 * MB);  // 16-40   B..D
    unsigned short* vt      = (unsigned short*)(w + 40 * MB);  // 40-48   C..D
    unsigned short* ctxb    = (unsigned short*)(w + 48 * MB);  // 48-56   Dm..E
    unsigned short* Opb     = (unsigned short*)(w + 56 * MB);  // 56-72   D..Dm (bf16)
    float*          mAb     = (float*)(w + 72 * MB);           // 72-72.5 D..Dm
    float*          lAb     = (float*)(w + 73 * MB);           // 73-73.5 D..Dm
    unsigned short* woT     = (unsigned short*)(w + 74 * MB);  // 74-76   A..E
    unsigned short* woPb    = (unsigned short*)(w);            // 0-16    E..F (2 bf16 splits)
    float*          Out1    = (float*)(w + 64 * MB);           // 64-80   F..I
    unsigned short* out1b   = (unsigned short*)(w + 40 * MB);  // 40-48   F..G
    unsigned short* fhb     = (unsigned short*)(w + 80 * MB);  // 80-112  G..H
    unsigned short* w2T     = (unsigned short*)(w + 112 * MB); // 112-120 A..H
    unsigned short* w1T     = (unsigned short*)(w + 120 * MB); // 120-128 A..G
    unsigned short* f2Pb    = (unsigned short*)(w);            // 0-32    H..I (4 bf16 splits)

    dim3 blk(256);

    // --- A: fused prep (6 transposes + bias concat + x cast), one launch
    prep_kernel<<<dim3(5132), blk, 0, stream>>>(
        wq_w, wk_w, wv_w, wo_w, ffn_w1, ffn_w2, wq_b, wk_b, wv_b, x,
        wqkvT, woT, w1T, w2T, biasqkv, actb);

    // --- B: merged QKV projection -> bf16 packed (256x256 pipelined)
    gemm256_kernel<<<dim3(192), dim3(512), 0, stream>>>(actb, wqkvT, biasqkv, nullptr, qkvb,
                                                        NTOK, 3072, 1024, 1024, 1, 0, 1);
    // --- C: V transpose
    vtrans_kernel<<<dim3(SEQ / 64, N_HEADS, BATCH), blk, 0, stream>>>(qkvb, vt);

    // --- D: MFMA flash attention, split-S=2 (4-wave blocks), then merge
    attn_mfma_kernel<<<dim3(SEQ / 128, N_HEADS, BATCH * 2), blk, 0, stream>>>(
        qkvb, vt, mask, Opb, mAb, lAb);
    attn_merge_kernel<<<dim3((BATCH * N_HEADS * SEQ) / 16), blk, 0, stream>>>(
        Opb, mAb, lAb, ctxb);

    // --- E: output projection, split-K=2 -> bf16 partials; LN1 fused reduce
    gemm_bt_kernel<<<dim3(8, 32, 2), blk, 0, stream>>>(ctxb, woT, nullptr, nullptr, woPb,
                                                       NTOK, 1024, 1024, 512, 0, 1);
    reduce_ln_kernel<<<dim3(NTOK), blk, 0, stream>>>(woPb, 1, 2, wo_b, x, ln1_g, ln1_b,
                                                     Out1, out1b);
    // --- G: FFN1 (256x256 pipelined)
    gemm256_kernel<<<dim3(256), dim3(512), 0, stream>>>(out1b, w1T, ffn_b1, nullptr, fhb,
                                                        NTOK, D_FF, 1024, 1024, 1, 1, 1);
    // --- H: FFN2, split-K=4 -> bf16 partials
    gemm256_kernel<<<dim3(256), dim3(512), 0, stream>>>(fhb, w2T, nullptr, nullptr, f2Pb,
                                                        NTOK, 1024, 4096, 1024, 4, 0, 1);
    // --- I: LN2 fused with ffn2-reduce -> out
    reduce_ln_kernel<<<dim3(NTOK), blk, 0, stream>>>(f2Pb, 1, 4, ffn_b2, Out1, ln2_g, ln2_b,
                                                     out, nullptr);
}

// Round 14
// 244.220 us; speedup vs baseline: 1.2969x; 1.0162x over previous
//
#include <hip/hip_runtime.h>
#include <hip/hip_bf16.h>

#define D_MODEL 1024
#define N_HEADS 16
#define DEPTH   64
#define D_FF    4096
#define BATCH   2
#define SEQ     2048
#define NTOK    (BATCH * SEQ)   // 4096
#define EPS     1e-5f

typedef __attribute__((ext_vector_type(8))) short short8;
typedef __attribute__((ext_vector_type(4))) float f32x4;
typedef __attribute__((ext_vector_type(4))) unsigned short ushort4v;
typedef __attribute__((ext_vector_type(8))) unsigned short ushort8v;

__device__ __forceinline__ unsigned short f2bf(float f) {
    union { __hip_bfloat16 h; unsigned short u; } cv;
    cv.h = __float2bfloat16(f);   // RNE
    return cv.u;
}

__device__ __forceinline__ float bf2f(unsigned short u) {
    union { float f; unsigned int i; } c;
    c.i = (unsigned int)u << 16;
    return c.f;
}

__device__ __forceinline__ float exp2_fast(float x) {
    float r;
    asm("v_exp_f32 %0, %1" : "=v"(r) : "v"(x));
    return r;
}

__device__ __forceinline__ void gload16(const unsigned short* g, unsigned short* lds) {
    __builtin_amdgcn_global_load_lds(
        (const __attribute__((address_space(1))) void*)g,
        (__attribute__((address_space(3))) void*)lds, 16, 0, 0);
}

// ---------------------------------------------------------------------------
// fused prep: all weight transposes (f32->bf16), bias concat, x cast.
// ---------------------------------------------------------------------------
__device__ __forceinline__ void tc_tile(
    const float* __restrict__ W, unsigned short* __restrict__ WT,
    int K, int N, int bn64, int bk64, int tid, float (*t)[65])
{
    const int bk = bk64 * 64, bn = bn64 * 64;
    const int c4 = tid & 15, r0 = tid >> 4;
#pragma unroll
    for (int i = 0; i < 4; ++i) {
        int k = r0 + i * 16;
        f32x4 v = *(const f32x4*)&W[(size_t)(bk + k) * N + bn + c4 * 4];
#pragma unroll
        for (int jj = 0; jj < 4; ++jj) t[k][c4 * 4 + jj] = v[jj];
    }
    __syncthreads();
#pragma unroll
    for (int i = 0; i < 4; ++i) {
        int n = r0 + i * 16;
        ushort4v o;
#pragma unroll
        for (int jj = 0; jj < 4; ++jj) o[jj] = f2bf(t[c4 * 4 + jj][n]);
        *(ushort4v*)&WT[(size_t)(bn + n) * K + bk + c4 * 4] = o;
    }
}

__global__ __launch_bounds__(256) void prep_kernel(
    const float* __restrict__ wq_w, const float* __restrict__ wk_w,
    const float* __restrict__ wv_w, const float* __restrict__ wo_w,
    const float* __restrict__ ffn_w1, const float* __restrict__ ffn_w2,
    const float* __restrict__ wq_b, const float* __restrict__ wk_b,
    const float* __restrict__ wv_b, const float* __restrict__ x,
    unsigned short* __restrict__ wqkvT, unsigned short* __restrict__ woT,
    unsigned short* __restrict__ w1T, unsigned short* __restrict__ w2T,
    float* __restrict__ biasqkv, unsigned short* __restrict__ actb)
{
    __shared__ float t[64][65];
    const int idx = blockIdx.x, tid = threadIdx.x;

    if (idx < 1024) {
        const int wsel = idx >> 8, rel = idx & 255;
        const float* W = (wsel == 0) ? wq_w : (wsel == 1) ? wk_w : (wsel == 2) ? wv_w : wo_w;
        unsigned short* WT = (wsel == 3) ? woT : (wqkvT + (size_t)wsel * 1024 * 1024);
        tc_tile(W, WT, 1024, 1024, rel & 15, rel >> 4, tid, t);
    } else if (idx < 2048) {
        const int rel = idx - 1024;
        tc_tile(ffn_w1, w1T, 1024, 4096, rel & 63, rel >> 6, tid, t);
    } else if (idx < 3072) {
        const int rel = idx - 2048;
        tc_tile(ffn_w2, w2T, 4096, 1024, rel & 15, rel >> 4, tid, t);
    } else if (idx < 3084) {
        const int i = (idx - 3072) * 256 + tid;
        if (i < 1024) biasqkv[i] = wq_b[i];
        else if (i < 2048) biasqkv[i] = wk_b[i - 1024];
        else if (i < 3072) biasqkv[i] = wv_b[i - 2048];
    } else {
        const int i = ((idx - 3084) * 256 + tid) * 8;
        f32x4 a = *(const f32x4*)&x[i];
        f32x4 b = *(const f32x4*)&x[i + 4];
        ushort8v o;
        o[0] = f2bf(a[0]); o[1] = f2bf(a[1]); o[2] = f2bf(a[2]); o[3] = f2bf(a[3]);
        o[4] = f2bf(b[0]); o[5] = f2bf(b[1]); o[6] = f2bf(b[2]); o[7] = f2bf(b[3]);
        *(ushort8v*)&actb[i] = o;
    }
}

// ---------------------------------------------------------------------------
// V^T extraction: QKV bf16 [tok][3072] (V at col 2048+) -> Vt[bh][64][2048]
// ---------------------------------------------------------------------------
__global__ __launch_bounds__(256) void vtrans_kernel(
    const unsigned short* __restrict__ QKV, unsigned short* __restrict__ Vt)
{
    __shared__ unsigned short T[64][72];
    const int st = blockIdx.x * 64;
    const int h = blockIdx.y, b = blockIdx.z;
    const int tid = threadIdx.x;
    const size_t tok0 = (size_t)b * SEQ;
    const int LD = 3 * D_MODEL;
    const int r = tid >> 3, c8 = (tid & 7) * 8;
#pragma unroll
    for (int p = 0; p < 2; ++p) {
        int row = p * 32 + r;
        *(ushort8v*)&T[row][c8] =
            *(const ushort8v*)&QKV[(tok0 + st + row) * LD + 2048 + h * 64 + c8];
    }
    __syncthreads();
    const int bh = b * N_HEADS + h;
#pragma unroll
    for (int p = 0; p < 2; ++p) {
        int d = p * 32 + r;
        ushort8v o;
#pragma unroll
        for (int e = 0; e < 8; ++e) o[e] = T[c8 + e][d];
        *(ushort8v*)&Vt[((size_t)bh * 64 + d) * SEQ + st + c8] = o;
    }
}

// ---------------------------------------------------------------------------
// 256x256 pipelined bf16 MFMA GEMM with optional split-K.
// ---------------------------------------------------------------------------
__global__ __launch_bounds__(512, 2) void gemm256_kernel(
    const unsigned short* __restrict__ A, const unsigned short* __restrict__ BT,
    const float* __restrict__ bias, float* __restrict__ C,
    unsigned short* __restrict__ Cb,
    int M, int N, int lda, int kLen, int ksplit, int relu, int out_bf)
{
    __shared__ unsigned short As[2][256 * 64];
    __shared__ unsigned short Bs[2][256 * 64];
    const int tid = threadIdx.x;
    const int lane = tid & 63, w = tid >> 6;
    const int wr = w >> 2, wc = w & 3;
    const int lr = lane & 15, g = lane >> 4;

    // XCD-aware block swizzle (bijective when nwg % 8 == 0)
    const int nwg = gridDim.x;
    int wg = blockIdx.x;
    if ((nwg & 7) == 0) wg = (wg & 7) * (nwg >> 3) + (wg >> 3);
    if (ksplit > 1) {
        const int ntile = nwg / ksplit;
        const int split = wg / ntile;
        wg = wg % ntile;
        A  += (size_t)split * kLen;
        BT += (size_t)split * kLen;
        C  += (size_t)split * M * N;
        Cb += (size_t)split * M * N;
    }
    const int gx = N >> 8;
    const int bm = (wg / gx) * 256, bn = (wg % gx) * 256;

    const int srow = (w << 3) + (lane >> 3);
    const int scol = ((lane & 7) ^ (lane >> 3)) << 3;
    const int ldst = (w << 9);

#define STG(P, Xs, bufi, hf, rb, k0)                                            \
    {                                                                            \
        gload16(P + (size_t)((rb) + (hf) * 128 + srow) * lda + (k0) + scol,      \
                &Xs[bufi][(hf) * 8192 + ldst]);                                  \
        gload16(P + (size_t)((rb) + (hf) * 128 + 64 + srow) * lda + (k0) + scol, \
                &Xs[bufi][(hf) * 8192 + 4096 + ldst]);                           \
    }

    const int NS = kLen >> 6;
    f32x4 acc[8][4] = {};

    STG(A,  As, 0, 0, bm, 0); STG(A,  As, 0, 1, bm, 0);
    STG(BT, Bs, 0, 0, bn, 0); STG(BT, Bs, 0, 1, bn, 0);
    if (NS > 1) { STG(BT, Bs, 1, 0, bn, 64); STG(BT, Bs, 1, 1, bn, 64); }
    asm volatile("s_waitcnt vmcnt(4)" ::: "memory");
    __builtin_amdgcn_s_barrier();
    asm volatile("" ::: "memory");

    int buf = 0;
    short8 af[4][2], b0[2][2], b1[2][2];
    for (int s = 0; s < NS; ++s) {
        const int kn1 = (s + 1) << 6, kn2 = (s + 2) << 6;

        // ---- phase 1
#pragma unroll
        for (int i = 0; i < 4; ++i)
#pragma unroll
            for (int kk = 0; kk < 2; ++kk)
                af[i][kk] = *(const short8*)&As[buf][(wr * 128 + i * 16 + lr) * 64
                                                    + (((kk * 4 + g) ^ (lr & 7)) << 3)];
#pragma unroll
        for (int j = 0; j < 2; ++j)
#pragma unroll
            for (int kk = 0; kk < 2; ++kk)
                b0[j][kk] = *(const short8*)&Bs[buf][(wc * 64 + j * 16 + lr) * 64
                                                    + (((kk * 4 + g) ^ (lr & 7)) << 3)];
        if (s + 1 < NS) STG(A, As, buf ^ 1, 0, bm, kn1);
        asm volatile("" ::: "memory");
        __builtin_amdgcn_s_barrier();
        asm volatile("" ::: "memory");
        __builtin_amdgcn_s_setprio(1);
#pragma unroll
        for (int i = 0; i < 4; ++i)
#pragma unroll
            for (int j = 0; j < 2; ++j) {
                acc[i][j] = __builtin_amdgcn_mfma_f32_16x16x32_bf16(af[i][0], b0[j][0], acc[i][j], 0, 0, 0);
                acc[i][j] = __builtin_amdgcn_mfma_f32_16x16x32_bf16(af[i][1], b0[j][1], acc[i][j], 0, 0, 0);
            }
        __builtin_amdgcn_s_setprio(0);
        asm volatile("" ::: "memory");
        __builtin_amdgcn_s_barrier();
        asm volatile("" ::: "memory");

        // ---- phase 2
#pragma unroll
        for (int j = 0; j < 2; ++j)
#pragma unroll
            for (int kk = 0; kk < 2; ++kk)
                b1[j][kk] = *(const short8*)&Bs[buf][(wc * 64 + (j + 2) * 16 + lr) * 64
                                                    + (((kk * 4 + g) ^ (lr & 7)) << 3)];
        if (s + 1 < NS) STG(A, As, buf ^ 1, 1, bm, kn1);
        asm volatile("" ::: "memory");
        __builtin_amdgcn_s_barrier();
        asm volatile("" ::: "memory");
        __builtin_amdgcn_s_setprio(1);
#pragma unroll
        for (int i = 0; i < 4; ++i)
#pragma unroll
            for (int j = 0; j < 2; ++j) {
                acc[i][j + 2] = __builtin_amdgcn_mfma_f32_16x16x32_bf16(af[i][0], b1[j][0], acc[i][j + 2], 0, 0, 0);
                acc[i][j + 2] = __builtin_amdgcn_mfma_f32_16x16x32_bf16(af[i][1], b1[j][1], acc[i][j + 2], 0, 0, 0);
            }
        __builtin_amdgcn_s_setprio(0);
        asm volatile("" ::: "memory");
        __builtin_amdgcn_s_barrier();
        asm volatile("" ::: "memory");

        // ---- phase 3
#pragma unroll
        for (int i = 0; i < 4; ++i)
#pragma unroll
            for (int kk = 0; kk < 2; ++kk)
                af[i][kk] = *(const short8*)&As[buf][(wr * 128 + 64 + i * 16 + lr) * 64
                                                    + (((kk * 4 + g) ^ (lr & 7)) << 3)];
        if (s + 2 < NS) STG(BT, Bs, buf, 0, bn, kn2);
        asm volatile("" ::: "memory");
        __builtin_amdgcn_s_barrier();
        asm volatile("" ::: "memory");
        __builtin_amdgcn_s_setprio(1);
#pragma unroll
        for (int i = 0; i < 4; ++i)
#pragma unroll
            for (int j = 0; j < 2; ++j) {
                acc[i + 4][j] = __builtin_amdgcn_mfma_f32_16x16x32_bf16(af[i][0], b0[j][0], acc[i + 4][j], 0, 0, 0);
                acc[i + 4][j] = __builtin_amdgcn_mfma_f32_16x16x32_bf16(af[i][1], b0[j][1], acc[i + 4][j], 0, 0, 0);
            }
        __builtin_amdgcn_s_setprio(0);
        asm volatile("" ::: "memory");
        __builtin_amdgcn_s_barrier();
        asm volatile("" ::: "memory");

        // ---- phase 4
        if (s + 2 < NS) STG(BT, Bs, buf, 1, bn, kn2);
        asm volatile("" ::: "memory");
        __builtin_amdgcn_s_barrier();
        asm volatile("" ::: "memory");
        __builtin_amdgcn_s_setprio(1);
#pragma unroll
        for (int i = 0; i < 4; ++i)
#pragma unroll
            for (int j = 0; j < 2; ++j) {
                acc[i + 4][j + 2] = __builtin_amdgcn_mfma_f32_16x16x32_bf16(af[i][0], b1[j][0], acc[i + 4][j + 2], 0, 0, 0);
                acc[i + 4][j + 2] = __builtin_amdgcn_mfma_f32_16x16x32_bf16(af[i][1], b1[j][1], acc[i + 4][j + 2], 0, 0, 0);
            }
        __builtin_amdgcn_s_setprio(0);
        asm volatile("s_waitcnt vmcnt(4)" ::: "memory");
        __builtin_amdgcn_s_barrier();
        asm volatile("" ::: "memory");

        buf ^= 1;
    }
#undef STG

#pragma unroll
    for (int i = 0; i < 8; ++i)
#pragma unroll
        for (int j = 0; j < 4; ++j) {
            const int col = bn + wc * 64 + j * 16 + lr;
            const float bv = bias ? bias[col] : 0.f;
#pragma unroll
            for (int r = 0; r < 4; ++r) {
                const int row = bm + wr * 128 + i * 16 + g * 4 + r;
                float v = acc[i][j][r] + bv;
                if (relu) v = fmaxf(v, 0.f);
                if (out_bf) Cb[(size_t)row * N + col] = f2bf(v);
                else        C [(size_t)row * N + col] = v;
            }
        }
}

// ---------------------------------------------------------------------------
// bf16 MFMA GEMM (m97 structure), 128x128 tile, optional split-K via blockIdx.z
// ---------------------------------------------------------------------------
__global__ __launch_bounds__(256) void gemm_bt_kernel(
    const unsigned short* __restrict__ A, const unsigned short* __restrict__ BT,
    const float* __restrict__ bias, float* __restrict__ C,
    unsigned short* __restrict__ Cb,
    int M, int N, int lda, int kLen, int relu, int out_bf)
{
    __shared__ unsigned short As[128 * 64];
    __shared__ unsigned short Bs[128 * 64];
    const int tid = threadIdx.x;
    const int lane = tid & 63, wv = tid >> 6;
    const int wr = wv >> 1, wc = wv & 1;
    const int bm = blockIdx.y * 128, bn = blockIdx.x * 128;
    const int kbase = blockIdx.z * kLen;
    const int lr = lane & 15, lk = (lane >> 4) << 3;

    C  += (size_t)blockIdx.z * M * N;
    Cb += (size_t)blockIdx.z * M * N;

    f32x4 acc[4][4] = {};

    for (int kt = 0; kt < kLen; kt += 64) {
#pragma unroll
        for (int c = 0; c < 4; ++c) {
            int e = c * 2048 + tid * 8;
            int row = e >> 6, k = e & 63;
            gload16(A  + (size_t)(bm + row) * lda + kbase + kt + k, As + c * 2048 + wv * 512);
            gload16(BT + (size_t)(bn + row) * lda + kbase + kt + k, Bs + c * 2048 + wv * 512);
        }
        __syncthreads();
#pragma unroll
        for (int kk = 0; kk < 2; ++kk) {
            short8 af[4], bfr[4];
#pragma unroll
            for (int i = 0; i < 4; ++i) {
                af[i]  = *(const short8*)&As[(wr * 64 + i * 16 + lr) * 64 + kk * 32 + lk];
                bfr[i] = *(const short8*)&Bs[(wc * 64 + i * 16 + lr) * 64 + kk * 32 + lk];
            }
#pragma unroll
            for (int i = 0; i < 4; ++i)
#pragma unroll
                for (int j = 0; j < 4; ++j)
                    acc[i][j] = __builtin_amdgcn_mfma_f32_16x16x32_bf16(
                        af[i], bfr[j], acc[i][j], 0, 0, 0);
        }
        __syncthreads();
    }

    const int r0 = bm + wr * 64, c0 = bn + wc * 64;
    const int rq = (lane >> 4) * 4;
#pragma unroll
    for (int i = 0; i < 4; ++i)
#pragma unroll
        for (int j = 0; j < 4; ++j) {
            int col = c0 + j * 16 + lr;
            float bv = bias ? bias[col] : 0.f;
#pragma unroll
            for (int r = 0; r < 4; ++r) {
                int row = r0 + i * 16 + rq + r;
                float v = acc[i][j][r] + bv;
                if (relu) v = fmaxf(v, 0.f);
                if (out_bf) Cb[(size_t)row * N + col] = f2bf(v);
                else        C [(size_t)row * N + col] = v;
            }
        }
}

// ---------------------------------------------------------------------------
// MFMA flash attention, split-S=2, 2 q-halves per block (block = 256 q rows).
// 4 waves; each wave owns 32 q per half (64 total). KVBLK=64, staged once per
// tile via gload_lds and consumed by BOTH q-halves (halves the K/V streaming
// and doubles compute per prefetch). Deferred-max online softmax (stale m_,
// init 20); rescale (rare) after PV. Row-sum l via ones-matrix MFMA.
// Outputs unnormalized O (bf16) + m + l per q-row.
// ---------------------------------------------------------------------------
__global__ __launch_bounds__(256, 2) void attn_mfma_kernel(
    const unsigned short* __restrict__ QKV,
    const unsigned short* __restrict__ Vt,
    const int* __restrict__ mask,
    unsigned short* __restrict__ Op, float* __restrict__ mA, float* __restrict__ lA)
{
    const int tid = threadIdx.x;
    const int lane = tid & 63, w = tid >> 6;
    const int lr = lane & 15, g = lane >> 4;   // g in 0..3
    const int qt = blockIdx.x * 256;
    const int h = blockIdx.y;
    const int b = blockIdx.z >> 1, sp = blockIdx.z & 1;
    const int bh = b * N_HEADS + h;
    const size_t tok0 = (size_t)b * SEQ;
    const int kvb0 = sp * (SEQ / 2);
    const int LD = 3 * D_MODEL;
    const float C1 = 0.18033688f;   // 0.125 * log2(e)

    __shared__ unsigned short Ks[2][64 * 64];   // [kv][d], 16B-slot swizzled
    __shared__ unsigned short Vs[2][64 * 64];   // [d][kv], 16B-slot swizzled
    __shared__ unsigned short Ps[4][32 * 64];   // per-wave P [q][kv], swizzled
    __shared__ float Msk[2][64];

    short8 onesB;
#pragma unroll
    for (int e = 0; e < 8; ++e) onesB[e] = (short)0x3F80;   // bf16 1.0

    // Q fragments for both halves: q = half*128 + w*32 + i*16 + lr
    short8 qf[2][2][2];
#pragma unroll
    for (int hf = 0; hf < 2; ++hf)
#pragma unroll
        for (int i = 0; i < 2; ++i)
#pragma unroll
            for (int kk = 0; kk < 2; ++kk)
                qf[hf][i][kk] = *(const short8*)&QKV[
                    (tok0 + qt + hf * 128 + w * 32 + i * 16 + lr) * LD
                    + h * 64 + kk * 32 + g * 8];

    const int rsub = w * 8 + (lane >> 3);
    const int slot = lane & 7;

    float m_[2][2] = {{20.f, 20.f}, {20.f, 20.f}};
    f32x4 lacc[2][2] = {};
    f32x4 o_[2][2][4] = {};

    {
#pragma unroll
        for (int p = 0; p < 2; ++p) {
            const int row = p * 32 + rsub;
            const int ss = slot ^ (row & 7);
            gload16(QKV + (tok0 + kvb0 + row) * LD + D_MODEL + h * 64 + ss * 8,
                    &Ks[0][(p * 32 + w * 8) * 64]);
            gload16(Vt + ((size_t)bh * 64 + row) * SEQ + kvb0 + ss * 8,
                    &Vs[0][(p * 32 + w * 8) * 64]);
        }
        if (tid < 64) Msk[0][tid] = mask[b * SEQ + kvb0 + tid] ? 0.f : -1e9f;
    }
    __syncthreads();

    const int NT = (SEQ / 2) / 64;   // 16
    int buf = 0;
    for (int t = 0; t < NT; ++t) {
        if (t + 1 < NT) {
            const int nb = buf ^ 1;
            const int kvn = kvb0 + (t + 1) * 64;
#pragma unroll
            for (int p = 0; p < 2; ++p) {
                const int row = p * 32 + rsub;
                const int ss = slot ^ (row & 7);
                gload16(QKV + (tok0 + kvn + row) * LD + D_MODEL + h * 64 + ss * 8,
                        &Ks[nb][(p * 32 + w * 8) * 64]);
                gload16(Vt + ((size_t)bh * 64 + row) * SEQ + kvn + ss * 8,
                        &Vs[nb][(p * 32 + w * 8) * 64]);
            }
            if (tid < 64) Msk[nb][tid] = mask[b * SEQ + kvn + tid] ? 0.f : -1e9f;
        }

        float mb[4][4];
#pragma unroll
        for (int j = 0; j < 4; ++j) {
            f32x4 mrow = *(const f32x4*)&Msk[buf][j * 16 + g * 4];
#pragma unroll
            for (int r = 0; r < 4; ++r) mb[j][r] = mrow[r];
        }

#pragma unroll
        for (int hf = 0; hf < 2; ++hf) {
            // ---- QK^T (swapped): sacc[i][j][r] = S[kv=j*16+g*4+r][q=i*16+lr]
            f32x4 sacc[2][4] = {};
#pragma unroll
            for (int j = 0; j < 4; ++j) {
                short8 kf0 = *(const short8*)&Ks[buf][(j * 16 + lr) * 64 + ((0 + g) ^ (lr & 7)) * 8];
                short8 kf1 = *(const short8*)&Ks[buf][(j * 16 + lr) * 64 + ((4 + g) ^ (lr & 7)) * 8];
#pragma unroll
                for (int i = 0; i < 2; ++i) {
                    sacc[i][j] = __builtin_amdgcn_mfma_f32_16x16x32_bf16(kf0, qf[hf][i][0], sacc[i][j], 0, 0, 0);
                    sacc[i][j] = __builtin_amdgcn_mfma_f32_16x16x32_bf16(kf1, qf[hf][i][1], sacc[i][j], 0, 0, 0);
                }
            }

            // ---- softmax: exp with STALE m_ (no wait on cross-lane max)
            float tmv[2];
#pragma unroll
            for (int i = 0; i < 2; ++i) {
                float x[4][4];
                float tm = -1e30f;
#pragma unroll
                for (int j = 0; j < 4; ++j)
#pragma unroll
                    for (int r = 0; r < 4; ++r) {
                        x[j][r] = fmaf(sacc[i][j][r], C1, mb[j][r]);
                        tm = fmaxf(tm, x[j][r]);
                    }
#pragma unroll
                for (int j = 0; j < 4; ++j) {
                    ushort4v pw;
#pragma unroll
                    for (int r = 0; r < 4; ++r)
                        pw[r] = f2bf(exp2_fast(x[j][r] - m_[hf][i]));
                    *(ushort4v*)((char*)&Ps[w][0] + (i * 16 + lr) * 128
                                 + ((j * 32 + g * 8) ^ ((lr & 7) << 4))) = pw;
                }
                tm = fmaxf(tm, __shfl_xor(tm, 16));
                tm = fmaxf(tm, __shfl_xor(tm, 32));
                tmv[i] = tm;
            }

            // ---- PV + l: O += P@V ; l += P@ones (same C layout as O)
#pragma unroll
            for (int kk = 0; kk < 2; ++kk) {
                short8 pf[2];
#pragma unroll
                for (int i = 0; i < 2; ++i) {
                    pf[i] = *(const short8*)&Ps[w][(i * 16 + lr) * 64 + ((kk * 4 + g) ^ (lr & 7)) * 8];
                    lacc[hf][i] = __builtin_amdgcn_mfma_f32_16x16x32_bf16(pf[i], onesB, lacc[hf][i], 0, 0, 0);
                }
#pragma unroll
                for (int dj = 0; dj < 4; ++dj) {
                    short8 vf = *(const short8*)&Vs[buf][(dj * 16 + lr) * 64 + ((kk * 4 + g) ^ (lr & 7)) * 8];
#pragma unroll
                    for (int i = 0; i < 2; ++i)
                        o_[hf][i][dj] = __builtin_amdgcn_mfma_f32_16x16x32_bf16(pf[i], vf, o_[hf][i][dj], 0, 0, 0);
                }
            }

            // ---- deferred rescale (rare): uniform post-scaling is exact
#pragma unroll
            for (int i = 0; i < 2; ++i) {
                if (__any(tmv[i] > m_[hf][i] + 8.f)) {
                    const float nm = fmaxf(m_[hf][i], tmv[i]);
                    const float sc = exp2_fast(m_[hf][i] - nm);
                    m_[hf][i] = nm;
#pragma unroll
                    for (int r = 0; r < 4; ++r) {
                        const float s_r = __shfl(sc, g * 4 + r);
                        lacc[hf][i][r] *= s_r;
#pragma unroll
                        for (int dj = 0; dj < 4; ++dj) o_[hf][i][dj][r] *= s_r;
                    }
                }
            }
        }

        __syncthreads();   // drains gloads (vmcnt) + all LDS reads of buf
        buf ^= 1;
    }

    // ---- epilogue: write unnormalized O (bf16) + m + l (shuffle-free)
    const int rowbase = (sp * 32 + bh) * 2048;
#pragma unroll
    for (int hf = 0; hf < 2; ++hf)
#pragma unroll
        for (int i = 0; i < 2; ++i) {
            const int qb = qt + hf * 128 + w * 32 + i * 16;
#pragma unroll
            for (int r = 0; r < 4; ++r) {
                const int q = qb + g * 4 + r;
                unsigned short* op = Op + (size_t)(rowbase + q) * 64;
#pragma unroll
                for (int dj = 0; dj < 4; ++dj) op[dj * 16 + lr] = f2bf(o_[hf][i][dj][r]);
            }
            if (g == 0) mA[rowbase + qb + lr] = m_[hf][i];
            if (lr == 0) {
#pragma unroll
                for (int r = 0; r < 4; ++r)
                    lA[rowbase + qb + g * 4 + r] = lacc[hf][i][r];
            }
        }
}

// ---------------------------------------------------------------------------
// merge 2 attention splits (bf16 partials) -> bf16 ctx [tok][1024]
// ---------------------------------------------------------------------------
__global__ __launch_bounds__(256) void attn_merge_kernel(
    const unsigned short* __restrict__ Op, const float* __restrict__ mA,
    const float* __restrict__ lA, unsigned short* __restrict__ ctx)
{
    const int tid = threadIdx.x;
    const int row = blockIdx.x * 16 + (tid >> 4);   // bh*2048 + q, 0..65535
    const int d4 = (tid & 15) * 4;
    const int bh = row >> 11, q = row & 2047;
    const int b = bh >> 4, h = bh & 15;
    const float m0 = mA[row], m1 = mA[65536 + row];
    const float l0 = lA[row], l1 = lA[65536 + row];
    const float m = fmaxf(m0, m1);
    const float a0 = exp2_fast(m0 - m), a1 = exp2_fast(m1 - m);
    const float inv = 1.f / (l0 * a0 + l1 * a1);
    ushort4v O0 = *(const ushort4v*)&Op[(size_t)row * 64 + d4];
    ushort4v O1 = *(const ushort4v*)&Op[((size_t)65536 + row) * 64 + d4];
    ushort4v o;
#pragma unroll
    for (int e = 0; e < 4; ++e)
        o[e] = f2bf((bf2f(O0[e]) * a0 + bf2f(O1[e]) * a1) * inv);
    *(ushort4v*)&ctx[((size_t)(b * SEQ + q)) * D_MODEL + h * 64 + d4] = o;
}

// ---------------------------------------------------------------------------
// fused split-K reduce + residual + LayerNorm (f32 or bf16 partials)
// ---------------------------------------------------------------------------
__global__ __launch_bounds__(256) void reduce_ln_kernel(
    const void* __restrict__ P, int pbf, int nsplit, const float* __restrict__ bias,
    const float* __restrict__ X, const float* __restrict__ g,
    const float* __restrict__ be, float* __restrict__ out,
    unsigned short* __restrict__ outb)
{
    const int row = blockIdx.x, tid = threadIdx.x;
    __shared__ float red[4];
    const size_t MN = (size_t)NTOK * D_MODEL;
    const size_t base = (size_t)row * D_MODEL + tid * 4;

    f32x4 s = *(const f32x4*)(X + base);
    f32x4 bb = *(const f32x4*)(bias + tid * 4);
    s += bb;
    if (pbf) {
        const unsigned short* Pb = (const unsigned short*)P;
        for (int sp = 0; sp < nsplit; ++sp) {
            ushort4v pv = *(const ushort4v*)(Pb + sp * MN + base);
#pragma unroll
            for (int e = 0; e < 4; ++e) s[e] += bf2f(pv[e]);
        }
    } else {
        const float* Pf = (const float*)P;
        for (int sp = 0; sp < nsplit; ++sp)
            s += *(const f32x4*)(Pf + sp * MN + base);
    }

    float ls = s[0] + s[1] + s[2] + s[3];
#pragma unroll
    for (int o = 32; o > 0; o >>= 1) ls += __shfl_down(ls, o);
    if ((tid & 63) == 0) red[tid >> 6] = ls;
    __syncthreads();
    const float mu = (red[0] + red[1] + red[2] + red[3]) * (1.f / D_MODEL);
    __syncthreads();

    float d0 = s[0] - mu, d1 = s[1] - mu, d2 = s[2] - mu, d3 = s[3] - mu;
    float lv = d0 * d0 + d1 * d1 + d2 * d2 + d3 * d3;
#pragma unroll
    for (int o = 32; o > 0; o >>= 1) lv += __shfl_down(lv, o);
    if ((tid & 63) == 0) red[tid >> 6] = lv;
    __syncthreads();
    const float var = (red[0] + red[1] + red[2] + red[3]) * (1.f / D_MODEL);
    const float inv = rsqrtf(var + EPS);

    f32x4 gv = *(const f32x4*)(g + tid * 4);
    f32x4 bv = *(const f32x4*)(be + tid * 4);
    f32x4 o4 = {d0 * inv * gv[0] + bv[0], d1 * inv * gv[1] + bv[1],
                d2 * inv * gv[2] + bv[2], d3 * inv * gv[3] + bv[3]};
    *(f32x4*)(out + base) = o4;
    if (outb) {
        ushort4v ob = {f2bf(o4[0]), f2bf(o4[1]), f2bf(o4[2]), f2bf(o4[3])};
        *(ushort4v*)(outb + base) = ob;
    }
}

// ---------------------------------------------------------------------------
extern "C" void kernel_launch(void* const* d_in, const int* in_sizes, int n_in,
                              void* d_out, int out_size, void* d_ws, size_t ws_size,
                              hipStream_t stream) {
    const float* x      = (const float*)d_in[0];
    const int*   mask   = (const int*)  d_in[1];
    const float* wq_w   = (const float*)d_in[2];
    const float* wq_b   = (const float*)d_in[3];
    const float* wk_w   = (const float*)d_in[4];
    const float* wk_b   = (const float*)d_in[5];
    const float* wv_w   = (const float*)d_in[6];
    const float* wv_b   = (const float*)d_in[7];
    const float* wo_w   = (const float*)d_in[8];
    const float* wo_b   = (const float*)d_in[9];
    const float* ffn_w1 = (const float*)d_in[10];
    const float* ffn_b1 = (const float*)d_in[11];
    const float* ffn_w2 = (const float*)d_in[12];
    const float* ffn_b2 = (const float*)d_in[13];
    const float* ln1_g  = (const float*)d_in[14];
    const float* ln1_b  = (const float*)d_in[15];
    const float* ln2_g  = (const float*)d_in[16];
    const float* ln2_b  = (const float*)d_in[17];
    float* out = (float*)d_out;

    char* w = (char*)d_ws;
    const size_t MB = 1024 * 1024;
    // lifetime-audited layout (phases: A prep, B qkv, C vtrans, D attn,
    // Dm merge, E wo, F ln1, G ffn1, H ffn2, I ln2):
    unsigned short* actb    = (unsigned short*)(w);            // 0-8     A..B
    unsigned short* wqkvT   = (unsigned short*)(w + 8 * MB);   // 8-14    A..B
    float*          biasqkv = (float*)(w + 14 * MB);           // 14-16   A..B
    unsigned short* qkvb    = (unsigned short*)(w + 16 * MB);  // 16-40   B..D
    unsigned short* vt      = (unsigned short*)(w + 40 * MB);  // 40-48   C..D
    unsigned short* ctxb    = (unsigned short*)(w + 48 * MB);  // 48-56   Dm..E
    unsigned short* Opb     = (unsigned short*)(w + 56 * MB);  // 56-72   D..Dm (bf16)
    float*          mAb     = (float*)(w + 72 * MB);           // 72-72.5 D..Dm
    float*          lAb     = (float*)(w + 73 * MB);           // 73-73.5 D..Dm
    unsigned short* woT     = (unsigned short*)(w + 74 * MB);  // 74-76   A..E
    unsigned short* woPb    = (unsigned short*)(w);            // 0-16    E..F (2 bf16 splits)
    float*          Out1    = (float*)(w + 64 * MB);           // 64-80   F..I
    unsigned short* out1b   = (unsigned short*)(w + 40 * MB);  // 40-48   F..G
    unsigned short* fhb     = (unsigned short*)(w + 80 * MB);  // 80-112  G..H
    unsigned short* w2T     = (unsigned short*)(w + 112 * MB); // 112-120 A..H
    unsigned short* w1T     = (unsigned short*)(w + 120 * MB); // 120-128 A..G
    unsigned short* f2Pb    = (unsigned short*)(w);            // 0-32    H..I (4 bf16 splits)

    dim3 blk(256);

    // --- A: fused prep (6 transposes + bias concat + x cast), one launch
    prep_kernel<<<dim3(5132), blk, 0, stream>>>(
        wq_w, wk_w, wv_w, wo_w, ffn_w1, ffn_w2, wq_b, wk_b, wv_b, x,
        wqkvT, woT, w1T, w2T, biasqkv, actb);

    // --- B: merged QKV projection -> bf16 packed (256x256 pipelined)
    gemm256_kernel<<<dim3(192), dim3(512), 0, stream>>>(actb, wqkvT, biasqkv, nullptr, qkvb,
                                                        NTOK, 3072, 1024, 1024, 1, 0, 1);
    // --- C: V transpose
    vtrans_kernel<<<dim3(SEQ / 64, N_HEADS, BATCH), blk, 0, stream>>>(qkvb, vt);

    // --- D: MFMA flash attention, split-S=2, 256-q blocks (2 halves), merge
    attn_mfma_kernel<<<dim3(SEQ / 256, N_HEADS, BATCH * 2), blk, 0, stream>>>(
        qkvb, vt, mask, Opb, mAb, lAb);
    attn_merge_kernel<<<dim3((BATCH * N_HEADS * SEQ) / 16), blk, 0, stream>>>(
        Opb, mAb, lAb, ctxb);

    // --- E: output projection, split-K=2 -> bf16 partials; LN1 fused reduce
    gemm_bt_kernel<<<dim3(8, 32, 2), blk, 0, stream>>>(ctxb, woT, nullptr, nullptr, woPb,
                                                       NTOK, 1024, 1024, 512, 0, 1);
    reduce_ln_kernel<<<dim3(NTOK), blk, 0, stream>>>(woPb, 1, 2, wo_b, x, ln1_g, ln1_b,
                                                     Out1, out1b);
    // --- G: FFN1 (256x256 pipelined)
    gemm256_kernel<<<dim3(256), dim3(512), 0, stream>>>(out1b, w1T, ffn_b1, nullptr, fhb,
                                                        NTOK, D_FF, 1024, 1024, 1, 1, 1);
    // --- H: FFN2, split-K=4 -> bf16 partials
    gemm256_kernel<<<dim3(256), dim3(512), 0, stream>>>(fhb, w2T, nullptr, nullptr, f2Pb,
                                                        NTOK, 1024, 4096, 1024, 4, 0, 1);
    // --- I: LN2 fused with ffn2-reduce -> out
    reduce_ln_kernel<<<dim3(NTOK), blk, 0, stream>>>(f2Pb, 1, 4, ffn_b2, Out1, ln2_g, ln2_b,
                                                     out, nullptr);
}